// Round 1
// baseline (225.620 us; speedup 1.0000x reference)
//
#include <hip/hip_runtime.h>
#include <cstdint>
#include <cstddef>

#define Bc 4
#define Dd 192
#define Hh 192
#define Ww 192
#define KK 25
#define RR 12          // K//2
#define VOL (Bc*Dd*Hh*Ww)   // 28,311,552

// ---------------------------------------------------------------------------
// Kernel 0: per-(batch,axis) Gaussian kernels [B*3][25] + label mapping [128]
// ---------------------------------------------------------------------------
__global__ void setup_tables_kernel(const float* __restrict__ sigma01,
                                    const int* __restrict__ src,
                                    const int* __restrict__ dst,
                                    float* __restrict__ kern,
                                    int* __restrict__ mapping) {
    int t = threadIdx.x;
    if (t < 128) mapping[t] = 0;
    __syncthreads();
    if (t < 32) {
        int s = src[t];
        if (s >= 0 && s < 128) mapping[s] = dst[t];
    }
    if (t < Bc * 3) {
        float sig = sigma01[t] * 3.0f;          // MAX_SIGMA
        float s = fmaxf(sig, 1e-3f);
        float g[KK];
        float sum = 0.0f;
        #pragma unroll
        for (int i = 0; i < KK; i++) {
            float a = (float)(i - RR);
            float v = expf(-0.5f * a * a / (s * s));
            g[i] = v; sum += v;
        }
        float inv = 1.0f / sum;
        #pragma unroll
        for (int i = 0; i < KK; i++) {
            float v = g[i] * inv;
            if (sig < 0.01f) v = (i == RR) ? 1.0f : 0.0f;   // delta
            kern[t * KK + i] = v;
        }
    }
}

// ---------------------------------------------------------------------------
// Kernel 1: fused bias-field * exp + blur along W.  Block = (64,4): 4 h-rows.
// Each thread produces 3 consecutive w outputs via a 27-wide register window.
// ---------------------------------------------------------------------------
__global__ __launch_bounds__(256) void pass_w_kernel(
    const float* __restrict__ x, float* __restrict__ out,
    const float* __restrict__ kern, const float* __restrict__ sb) {
    __shared__ float s[4][Ww + 2 * RR];   // 4 x 216
    __shared__ float kk[KK];
    const int tx = threadIdx.x;           // 0..63
    const int ty = threadIdx.y;           // 0..3
    const int h0 = blockIdx.x * 4;
    const int d  = blockIdx.y;
    const int b  = blockIdx.z;
    const int tid = ty * 64 + tx;
    if (tid < KK) kk[tid] = kern[(b * 3 + 2) * KK + tid];   // axis W kernel

    const int h = h0 + ty;
    // trilinear (align_corners) coefficients: collapse d,h -> c[k] over w-nodes
    float pos_d = d * (3.0f / 191.0f);
    int   id0   = min((int)pos_d, 2);
    float fd    = pos_d - (float)id0;
    float pos_h = h * (3.0f / 191.0f);
    int   ih0   = min((int)pos_h, 2);
    float fh    = pos_h - (float)ih0;
    const float* sbb = sb + b * 64;
    float c0, c1, c2, c3;
    {
        float cv[4];
        #pragma unroll
        for (int k = 0; k < 4; k++) {
            float v00 = sbb[id0 * 16 + ih0 * 4 + k];
            float v01 = sbb[id0 * 16 + (ih0 + 1) * 4 + k];
            float v10 = sbb[(id0 + 1) * 16 + ih0 * 4 + k];
            float v11 = sbb[(id0 + 1) * 16 + (ih0 + 1) * 4 + k];
            cv[k] = (1.0f - fd) * ((1.0f - fh) * v00 + fh * v01)
                  +          fd * ((1.0f - fh) * v10 + fh * v11);
        }
        c0 = cv[0]; c1 = cv[1]; c2 = cv[2]; c3 = cv[3];
    }
    const size_t base = (((size_t)b * Dd + d) * Hh + h) * (size_t)Ww;
    // load + bias + exp (coalesced: w = e*64 + tx); hat-function weights (no
    // runtime-indexed register arrays -> no scratch)
    #pragma unroll
    for (int e = 0; e < 3; e++) {
        int w = e * 64 + tx;
        float pw = w * (3.0f / 191.0f);
        float w0 = fmaxf(0.0f, 1.0f - fabsf(pw - 0.0f));
        float w1 = fmaxf(0.0f, 1.0f - fabsf(pw - 1.0f));
        float w2 = fmaxf(0.0f, 1.0f - fabsf(pw - 2.0f));
        float w3 = fmaxf(0.0f, 1.0f - fabsf(pw - 3.0f));
        float bias = (w0 * c0 + w1 * c1 + w2 * c2 + w3 * c3) * 0.7f;
        s[ty][RR + w] = x[base + w] * expf(bias);
    }
    __syncthreads();
    if (tx < RR) {                       // replicate-pad halos
        s[ty][tx] = s[ty][RR];
        s[ty][RR + Ww + tx] = s[ty][RR + Ww - 1];
    }
    __syncthreads();
    // 3 consecutive outputs / thread, 27-wide window
    const int wb = tx * 3;
    float win[KK + 2];
    #pragma unroll
    for (int i = 0; i < KK + 2; i++) win[i] = s[ty][wb + i];
    float a0 = 0.f, a1 = 0.f, a2 = 0.f;
    #pragma unroll
    for (int t = 0; t < KK; t++) {
        float kv = kk[t];
        a0 += kv * win[t]; a1 += kv * win[t + 1]; a2 += kv * win[t + 2];
    }
    out[base + wb]     = a0;
    out[base + wb + 1] = a1;
    out[base + wb + 2] = a2;
}

// ---------------------------------------------------------------------------
// Kernel 2: blur along H. Block (64,4); tile = 32 h-outputs x 64 w.
// Each thread: 8 consecutive h outputs via 32-wide register window.
// ---------------------------------------------------------------------------
__global__ __launch_bounds__(256) void pass_h_kernel(
    const float* __restrict__ in, float* __restrict__ out,
    const float* __restrict__ kern) {
    __shared__ float s[32 + 2 * RR][64];   // 56 x 64
    __shared__ float kk[KK];
    const int tx = threadIdx.x, ty = threadIdx.y;
    const int w0 = blockIdx.x * 64;
    const int h0 = blockIdx.y * 32;
    const int bd = blockIdx.z;
    const int d = bd % Dd, b = bd / Dd;
    const int tid = ty * 64 + tx;
    if (tid < KK) kk[tid] = kern[(b * 3 + 1) * KK + tid];   // axis H kernel
    const size_t plane = ((size_t)b * Dd + d) * (size_t)(Hh * Ww);
    for (int r = ty; r < 56; r += 4) {
        int hh = min(max(h0 + r - RR, 0), Hh - 1);
        s[r][tx] = in[plane + (size_t)hh * Ww + w0 + tx];
    }
    __syncthreads();
    const int ob = ty * 8;
    float win[32];
    #pragma unroll
    for (int i = 0; i < 32; i++) win[i] = s[ob + i][tx];
    float acc[8];
    #pragma unroll
    for (int j = 0; j < 8; j++) acc[j] = 0.0f;
    #pragma unroll
    for (int t = 0; t < KK; t++) {
        float kv = kk[t];
        #pragma unroll
        for (int j = 0; j < 8; j++) acc[j] += kv * win[j + t];
    }
    #pragma unroll
    for (int j = 0; j < 8; j++)
        out[plane + (size_t)(h0 + ob + j) * Ww + w0 + tx] = acc[j];
}

// ---------------------------------------------------------------------------
// Kernel 3: blur along D. Same structure; rows stride by H*W.
// ---------------------------------------------------------------------------
__global__ __launch_bounds__(256) void pass_d_kernel(
    const float* __restrict__ in, float* __restrict__ out,
    const float* __restrict__ kern) {
    __shared__ float s[32 + 2 * RR][64];
    __shared__ float kk[KK];
    const int tx = threadIdx.x, ty = threadIdx.y;
    const int w0 = blockIdx.x * 64;
    const int d0 = blockIdx.y * 32;
    const int bh = blockIdx.z;
    const int h = bh % Hh, b = bh / Hh;
    const int tid = ty * 64 + tx;
    if (tid < KK) kk[tid] = kern[(b * 3 + 0) * KK + tid];   // axis D kernel
    for (int r = ty; r < 56; r += 4) {
        int dd = min(max(d0 + r - RR, 0), Dd - 1);
        s[r][tx] = in[(((size_t)b * Dd + dd) * Hh + h) * (size_t)Ww + w0 + tx];
    }
    __syncthreads();
    const int ob = ty * 8;
    float win[32];
    #pragma unroll
    for (int i = 0; i < 32; i++) win[i] = s[ob + i][tx];
    float acc[8];
    #pragma unroll
    for (int j = 0; j < 8; j++) acc[j] = 0.0f;
    #pragma unroll
    for (int t = 0; t < KK; t++) {
        float kv = kk[t];
        #pragma unroll
        for (int j = 0; j < 8; j++) acc[j] += kv * win[j + t];
    }
    #pragma unroll
    for (int j = 0; j < 8; j++)
        out[(((size_t)b * Dd + (d0 + ob + j)) * Hh + h) * (size_t)Ww + w0 + tx] = acc[j];
}

// ---------------------------------------------------------------------------
// Kernel 4: label remap -> written as float values (harness reads f32)
// ---------------------------------------------------------------------------
__global__ __launch_bounds__(256) void remap_kernel(
    const int4* __restrict__ labels, float4* __restrict__ out,
    const int* __restrict__ mapping, int n4) {
    int i = blockIdx.x * blockDim.x + threadIdx.x;
    int stride = gridDim.x * blockDim.x;
    for (; i < n4; i += stride) {
        int4 l = labels[i];
        float4 o;
        o.x = (float)mapping[min(max(l.x, 0), 127)];
        o.y = (float)mapping[min(max(l.y, 0), 127)];
        o.z = (float)mapping[min(max(l.z, 0), 127)];
        o.w = (float)mapping[min(max(l.w, 0), 127)];
        out[i] = o;
    }
}

extern "C" void kernel_launch(void* const* d_in, const int* in_sizes, int n_in,
                              void* d_out, int out_size, void* d_ws, size_t ws_size,
                              hipStream_t stream) {
    const float* x          = (const float*)d_in[0];
    const float* small_bias = (const float*)d_in[1];
    const float* sigma01    = (const float*)d_in[2];
    const int*   labels     = (const int*)d_in[3];
    const int*   src        = (const int*)d_in[4];
    const int*   dst        = (const int*)d_in[5];

    float* out     = (float*)d_out;
    float* img     = out;            // first VOL floats
    float* lab_out = out + (size_t)VOL; // second VOL floats
    float* tmp     = lab_out;        // reuse labels half as blur ping-pong buf

    float* kern    = (float*)d_ws;                    // 300 floats
    int*   mapping = (int*)((float*)d_ws + 384);      // 128 ints

    setup_tables_kernel<<<1, 128, 0, stream>>>(sigma01, src, dst, kern, mapping);

    dim3 blk(64, 4);
    // W-pass (fused bias*exp):  x -> img
    pass_w_kernel<<<dim3(Hh / 4, Dd, Bc), blk, 0, stream>>>(x, img, kern, small_bias);
    // H-pass: img -> tmp (labels half, overwritten later by remap)
    pass_h_kernel<<<dim3(Ww / 64, Hh / 32, Bc * Dd), blk, 0, stream>>>(img, tmp, kern);
    // D-pass: tmp -> img (final image)
    pass_d_kernel<<<dim3(Ww / 64, Dd / 32, Bc * Hh), blk, 0, stream>>>(tmp, img, kern);
    // labels remap (after pass_d has consumed tmp)
    remap_kernel<<<2048, 256, 0, stream>>>((const int4*)labels, (float4*)lab_out,
                                           mapping, VOL / 4);
}

// Round 2
// 190.511 us; speedup vs baseline: 1.1843x; 1.1843x over previous
//
#include <hip/hip_runtime.h>
#include <cstdint>
#include <cstddef>

#define Bc 4
#define Dd 192
#define Hh 192
#define Ww 192
#define KK 25
#define RR 12          // K//2
#define VOL (Bc*Dd*Hh*Ww)   // 28,311,552

typedef unsigned short u16;
typedef unsigned int   u32;

__device__ inline u16 f2bf(float f) {              // round-to-nearest-even
    u32 u = __float_as_uint(f);
    return (u16)((u + 0x7FFFu + ((u >> 16) & 1u)) >> 16);
}
__device__ inline float bfl(u32 u) { return __uint_as_float(u << 16); }
__device__ inline float bfh(u32 u) { return __uint_as_float(u & 0xFFFF0000u); }

// ---------------------------------------------------------------------------
// Kernel 0: per-(batch,axis) Gaussian kernels [B*3][25] + label mapping [128]
// ---------------------------------------------------------------------------
__global__ void setup_tables_kernel(const float* __restrict__ sigma01,
                                    const int* __restrict__ src,
                                    const int* __restrict__ dst,
                                    float* __restrict__ kern,
                                    int* __restrict__ mapping) {
    int t = threadIdx.x;
    if (t < 128) mapping[t] = 0;
    __syncthreads();
    if (t < 32) {
        int s = src[t];
        if (s >= 0 && s < 128) mapping[s] = dst[t];
    }
    if (t < Bc * 3) {
        float sig = sigma01[t] * 3.0f;          // MAX_SIGMA
        float s = fmaxf(sig, 1e-3f);
        float g[KK];
        float sum = 0.0f;
        #pragma unroll
        for (int i = 0; i < KK; i++) {
            float a = (float)(i - RR);
            float v = expf(-0.5f * a * a / (s * s));
            g[i] = v; sum += v;
        }
        float inv = 1.0f / sum;
        #pragma unroll
        for (int i = 0; i < KK; i++) {
            float v = g[i] * inv;
            if (sig < 0.01f) v = (i == RR) ? 1.0f : 0.0f;   // delta
            kern[t * KK + i] = v;
        }
    }
}

// ---------------------------------------------------------------------------
// Kernel 1: fused bias-field * exp + blur along W.  f32 in -> bf16 out.
// Block (64,4): 4 h-rows. 3 outputs/thread via 27-wide register window,
// repacked through LDS for one contiguous 1536 B uint4 store burst.
// ---------------------------------------------------------------------------
__global__ __launch_bounds__(256) void pass_w_kernel(
    const float* __restrict__ x, u16* __restrict__ outA,
    const float* __restrict__ kern, const float* __restrict__ sb) {
    __shared__ float s[4][Ww + 2 * RR];   // 4 x 216
    __shared__ u16 sOut[4 * Ww] __attribute__((aligned(16)));   // 1536 B
    __shared__ float kk[KK];
    const int tx = threadIdx.x;           // 0..63
    const int ty = threadIdx.y;           // 0..3
    const int h0 = blockIdx.x * 4;
    const int d  = blockIdx.y;
    const int b  = blockIdx.z;
    const int tid = ty * 64 + tx;
    if (tid < KK) kk[tid] = kern[(b * 3 + 2) * KK + tid];   // axis W kernel

    const int h = h0 + ty;
    // trilinear (align_corners) coefficients: collapse d,h -> c[k] over w-nodes
    float pos_d = d * (3.0f / 191.0f);
    int   id0   = min((int)pos_d, 2);
    float fd    = pos_d - (float)id0;
    float pos_h = h * (3.0f / 191.0f);
    int   ih0   = min((int)pos_h, 2);
    float fh    = pos_h - (float)ih0;
    const float* sbb = sb + b * 64;
    float c0, c1, c2, c3;
    {
        float cv[4];
        #pragma unroll
        for (int k = 0; k < 4; k++) {
            float v00 = sbb[id0 * 16 + ih0 * 4 + k];
            float v01 = sbb[id0 * 16 + (ih0 + 1) * 4 + k];
            float v10 = sbb[(id0 + 1) * 16 + ih0 * 4 + k];
            float v11 = sbb[(id0 + 1) * 16 + (ih0 + 1) * 4 + k];
            cv[k] = (1.0f - fd) * ((1.0f - fh) * v00 + fh * v01)
                  +          fd * ((1.0f - fh) * v10 + fh * v11);
        }
        c0 = cv[0]; c1 = cv[1]; c2 = cv[2]; c3 = cv[3];
    }
    const size_t base = (((size_t)b * Dd + d) * Hh + h) * (size_t)Ww;
    #pragma unroll
    for (int e = 0; e < 3; e++) {
        int w = e * 64 + tx;
        float pw = w * (3.0f / 191.0f);
        float w0 = fmaxf(0.0f, 1.0f - fabsf(pw - 0.0f));
        float w1 = fmaxf(0.0f, 1.0f - fabsf(pw - 1.0f));
        float w2 = fmaxf(0.0f, 1.0f - fabsf(pw - 2.0f));
        float w3 = fmaxf(0.0f, 1.0f - fabsf(pw - 3.0f));
        float bias = (w0 * c0 + w1 * c1 + w2 * c2 + w3 * c3) * 0.7f;
        s[ty][RR + w] = x[base + w] * expf(bias);
    }
    __syncthreads();
    if (tx < RR) {                       // replicate-pad halos
        s[ty][tx] = s[ty][RR];
        s[ty][RR + Ww + tx] = s[ty][RR + Ww - 1];
    }
    __syncthreads();
    const int wb = tx * 3;
    float win[KK + 2];
    #pragma unroll
    for (int i = 0; i < KK + 2; i++) win[i] = s[ty][wb + i];
    float a0 = 0.f, a1 = 0.f, a2 = 0.f;
    #pragma unroll
    for (int t = 0; t < KK; t++) {
        float kv = kk[t];
        a0 += kv * win[t]; a1 += kv * win[t + 1]; a2 += kv * win[t + 2];
    }
    sOut[ty * Ww + wb]     = f2bf(a0);
    sOut[ty * Ww + wb + 1] = f2bf(a1);
    sOut[ty * Ww + wb + 2] = f2bf(a2);
    __syncthreads();
    // 4 rows x 192 bf16 = 1536 B, contiguous in global (full-W rows, h adjacent)
    if (tid < 96) {
        const size_t ob = (((size_t)b * Dd + d) * Hh + h0) * (size_t)Ww;
        ((uint4*)(outA + ob))[tid] = ((const uint4*)sOut)[tid];
    }
}

// ---------------------------------------------------------------------------
// Kernel 2: blur along H. bf16 -> bf16. Block 256 flat.
// Tile: 32 h-outputs x full W=192; input rows 56 x 192 (contiguous block).
// ---------------------------------------------------------------------------
__global__ __launch_bounds__(256) void pass_h_kernel(
    const u16* __restrict__ in, u16* __restrict__ out,
    const float* __restrict__ kern) {
    __shared__ float sIn[56 * Ww];      // 43008 B
    __shared__ float kk[KK];
    const int tid = threadIdx.x;
    const int h0 = blockIdx.x * 32;
    const int bd = blockIdx.y;
    const int d = bd % Dd, b = bd / Dd;
    if (tid < KK) kk[tid] = kern[(b * 3 + 1) * KK + tid];   // axis H kernel
    const size_t plane = ((size_t)b * Dd + d) * (size_t)(Hh * Ww);
    // flat load: 56 rows x 24 uint4-chunks (16B = 8 bf16) per row
    #pragma unroll
    for (int k = 0; k < 6; k++) {
        int idx = tid + k * 256;
        if (idx < 56 * 24) {
            int r = idx / 24, seg = idx % 24;
            int hh = min(max(h0 + r - RR, 0), Hh - 1);
            uint4 v = *(const uint4*)(in + plane + (size_t)hh * Ww + seg * 8);
            float* p = &sIn[r * Ww + seg * 8];
            p[0] = bfl(v.x); p[1] = bfh(v.x);
            p[2] = bfl(v.y); p[3] = bfh(v.y);
            p[4] = bfl(v.z); p[5] = bfh(v.z);
            p[6] = bfl(v.w); p[7] = bfh(v.w);
        }
    }
    __syncthreads();
    const int tx = tid & 63;
    const int ob = (tid >> 6) * 8;      // 8 h-outputs per thread
    #pragma unroll
    for (int c = 0; c < 3; c++) {
        const int col = c * 64 + tx;
        float win[32];
        #pragma unroll
        for (int i = 0; i < 32; i++) win[i] = sIn[(ob + i) * Ww + col];
        float acc[8];
        #pragma unroll
        for (int j = 0; j < 8; j++) acc[j] = 0.0f;
        #pragma unroll
        for (int t = 0; t < KK; t++) {
            float kv = kk[t];
            #pragma unroll
            for (int j = 0; j < 8; j++) acc[j] += kv * win[j + t];
        }
        #pragma unroll
        for (int j = 0; j < 8; j++)
            out[plane + (size_t)(h0 + ob + j) * Ww + col] = f2bf(acc[j]);
    }
}

// ---------------------------------------------------------------------------
// Kernel 3: blur along D. bf16 -> f32 (final image). Same structure;
// input rows are 384 B contiguous segments strided by H*W.
// ---------------------------------------------------------------------------
__global__ __launch_bounds__(256) void pass_d_kernel(
    const u16* __restrict__ in, float* __restrict__ out,
    const float* __restrict__ kern) {
    __shared__ float sIn[56 * Ww];
    __shared__ float kk[KK];
    const int tid = threadIdx.x;
    const int d0 = blockIdx.x * 32;
    const int bh = blockIdx.y;
    const int h = bh % Hh, b = bh / Hh;
    if (tid < KK) kk[tid] = kern[(b * 3 + 0) * KK + tid];   // axis D kernel
    #pragma unroll
    for (int k = 0; k < 6; k++) {
        int idx = tid + k * 256;
        if (idx < 56 * 24) {
            int r = idx / 24, seg = idx % 24;
            int dd = min(max(d0 + r - RR, 0), Dd - 1);
            uint4 v = *(const uint4*)(in + (((size_t)b * Dd + dd) * Hh + h) * (size_t)Ww + seg * 8);
            float* p = &sIn[r * Ww + seg * 8];
            p[0] = bfl(v.x); p[1] = bfh(v.x);
            p[2] = bfl(v.y); p[3] = bfh(v.y);
            p[4] = bfl(v.z); p[5] = bfh(v.z);
            p[6] = bfl(v.w); p[7] = bfh(v.w);
        }
    }
    __syncthreads();
    const int tx = tid & 63;
    const int ob = (tid >> 6) * 8;      // 8 d-outputs per thread
    #pragma unroll
    for (int c = 0; c < 3; c++) {
        const int col = c * 64 + tx;
        float win[32];
        #pragma unroll
        for (int i = 0; i < 32; i++) win[i] = sIn[(ob + i) * Ww + col];
        float acc[8];
        #pragma unroll
        for (int j = 0; j < 8; j++) acc[j] = 0.0f;
        #pragma unroll
        for (int t = 0; t < KK; t++) {
            float kv = kk[t];
            #pragma unroll
            for (int j = 0; j < 8; j++) acc[j] += kv * win[j + t];
        }
        #pragma unroll
        for (int j = 0; j < 8; j++)
            out[(((size_t)b * Dd + (d0 + ob + j)) * Hh + h) * (size_t)Ww + col] = acc[j];
    }
}

// ---------------------------------------------------------------------------
// Kernel 4: label remap -> written as float values (harness reads f32)
// ---------------------------------------------------------------------------
__global__ __launch_bounds__(256) void remap_kernel(
    const int4* __restrict__ labels, float4* __restrict__ out,
    const int* __restrict__ mapping, int n4) {
    int i = blockIdx.x * blockDim.x + threadIdx.x;
    int stride = gridDim.x * blockDim.x;
    for (; i < n4; i += stride) {
        int4 l = labels[i];
        float4 o;
        o.x = (float)mapping[min(max(l.x, 0), 127)];
        o.y = (float)mapping[min(max(l.y, 0), 127)];
        o.z = (float)mapping[min(max(l.z, 0), 127)];
        o.w = (float)mapping[min(max(l.w, 0), 127)];
        out[i] = o;
    }
}

extern "C" void kernel_launch(void* const* d_in, const int* in_sizes, int n_in,
                              void* d_out, int out_size, void* d_ws, size_t ws_size,
                              hipStream_t stream) {
    const float* x          = (const float*)d_in[0];
    const float* small_bias = (const float*)d_in[1];
    const float* sigma01    = (const float*)d_in[2];
    const int*   labels     = (const int*)d_in[3];
    const int*   src        = (const int*)d_in[4];
    const int*   dst        = (const int*)d_in[5];

    float* out     = (float*)d_out;
    float* img     = out;                   // first VOL f32
    float* lab_out = out + (size_t)VOL;     // second VOL f32
    // two bf16 ping-pong volumes exactly fill the labels half (2*VOL*2B = VOL*4B)
    u16* A  = (u16*)lab_out;
    u16* Bb = A + (size_t)VOL;

    float* kern    = (float*)d_ws;                    // 300 floats
    int*   mapping = (int*)((float*)d_ws + 384);      // 128 ints

    setup_tables_kernel<<<1, 128, 0, stream>>>(sigma01, src, dst, kern, mapping);

    // W-pass (fused bias*exp): x(f32) -> A(bf16)
    pass_w_kernel<<<dim3(Hh / 4, Dd, Bc), dim3(64, 4), 0, stream>>>(x, A, kern, small_bias);
    // H-pass: A -> B (bf16)
    pass_h_kernel<<<dim3(Hh / 32, Bc * Dd), 256, 0, stream>>>(A, Bb, kern);
    // D-pass: B -> img (f32 final)
    pass_d_kernel<<<dim3(Dd / 32, Bc * Hh), 256, 0, stream>>>(Bb, img, kern);
    // labels remap (after pass_d consumed B; overwrites A/B region)
    remap_kernel<<<2048, 256, 0, stream>>>((const int4*)labels, (float4*)lab_out,
                                           mapping, VOL / 4);
}

// Round 3
// 180.160 us; speedup vs baseline: 1.2523x; 1.0575x over previous
//
#include <hip/hip_runtime.h>
#include <cstdint>
#include <cstddef>

#define Bc 4
#define Dd 192
#define Hh 192
#define Ww 192
#define KK 25
#define RR 12          // K//2
#define VOL (Bc*Dd*Hh*Ww)   // 28,311,552
#define P1S 194        // u16 row stride: 388 B = 97 banks -> conflict-free cols

typedef unsigned short u16;
typedef unsigned int   u32;

__device__ inline u16 f2bf(float f) {              // round-to-nearest-even
    u32 u = __float_as_uint(f);
    return (u16)((u + 0x7FFFu + ((u >> 16) & 1u)) >> 16);
}
__device__ inline float bf2f(u16 v) { return __uint_as_float(((u32)v) << 16); }

__device__ inline float hatdot(float p, float4 c) {
    float b0 = fmaxf(0.f, 1.f - fabsf(p));
    float b1 = fmaxf(0.f, 1.f - fabsf(p - 1.f));
    float b2 = fmaxf(0.f, 1.f - fabsf(p - 2.f));
    float b3 = fmaxf(0.f, 1.f - fabsf(p - 3.f));
    return b0 * c.x + b1 * c.y + b2 * c.z + b3 * c.w;
}

// ---------------------------------------------------------------------------
// Kernel 0: per-(batch,axis) Gaussian kernels [B*3][25] + label mapping [128]
// ---------------------------------------------------------------------------
__global__ void setup_tables_kernel(const float* __restrict__ sigma01,
                                    const int* __restrict__ src,
                                    const int* __restrict__ dst,
                                    float* __restrict__ kern,
                                    int* __restrict__ mapping) {
    int t = threadIdx.x;
    if (t < 128) mapping[t] = 0;
    __syncthreads();
    if (t < 32) {
        int s = src[t];
        if (s >= 0 && s < 128) mapping[s] = dst[t];
    }
    if (t < Bc * 3) {
        float sig = sigma01[t] * 3.0f;          // MAX_SIGMA
        float s = fmaxf(sig, 1e-3f);
        float g[KK];
        float sum = 0.0f;
        #pragma unroll
        for (int i = 0; i < KK; i++) {
            float a = (float)(i - RR);
            float v = expf(-0.5f * a * a / (s * s));
            g[i] = v; sum += v;
        }
        float inv = 1.0f / sum;
        #pragma unroll
        for (int i = 0; i < KK; i++) {
            float v = g[i] * inv;
            if (sig < 0.01f) v = (i == RR) ? 1.0f : 0.0f;   // delta
            kern[t * KK + i] = v;
        }
    }
}

// ---------------------------------------------------------------------------
// Kernel 1: FUSED bias*exp + W-blur + H-blur, one (b,d) plane per block.
// 512 threads, 77.6 KB LDS -> 2 blocks/CU. f32 in -> bf16 out (std layout).
// ---------------------------------------------------------------------------
__global__ __launch_bounds__(512, 4) void pass_wh_kernel(
    const float* __restrict__ x, u16* __restrict__ outB,
    const float* __restrict__ kern, const float* __restrict__ sb) {
    __shared__ u16 P1[Hh * P1S];                          // 74496 B
    __shared__ __attribute__((aligned(16))) float ch[Hh][4];  // 3072 B
    const int tid = threadIdx.x;
    const int d = blockIdx.x;
    const int b = blockIdx.y;

    // --- phase 0: per-h bias coefficients (d,h collapsed; *0.7 folded) ---
    if (tid < Hh) {
        float pos_d = d * (3.0f / 191.0f);
        int   id0   = min((int)pos_d, 2);
        float fd    = pos_d - (float)id0;
        float pos_h = tid * (3.0f / 191.0f);
        float h0w = fmaxf(0.f, 1.f - fabsf(pos_h));
        float h1w = fmaxf(0.f, 1.f - fabsf(pos_h - 1.f));
        float h2w = fmaxf(0.f, 1.f - fabsf(pos_h - 2.f));
        float h3w = fmaxf(0.f, 1.f - fabsf(pos_h - 3.f));
        const float* sbA = sb + b * 64 + id0 * 16;
        const float* sbB = sbA + 16;
        #pragma unroll
        for (int k = 0; k < 4; k++) {
            float sj0 = (1.f - fd) * sbA[k]      + fd * sbB[k];
            float sj1 = (1.f - fd) * sbA[4 + k]  + fd * sbB[4 + k];
            float sj2 = (1.f - fd) * sbA[8 + k]  + fd * sbB[8 + k];
            float sj3 = (1.f - fd) * sbA[12 + k] + fd * sbB[12 + k];
            ch[tid][k] = (h0w * sj0 + h1w * sj1 + h2w * sj2 + h3w * sj3) * 0.7f;
        }
    }
    __syncthreads();

    // --- phase 1: load plane, bias*exp, store bf16 to P1 ---
    const size_t xbase = ((size_t)b * Dd + d) * (size_t)(Hh * Ww);
    #pragma unroll
    for (int it = 0; it < 18; it++) {
        int idx4 = it * 512 + tid;            // 0..9215
        int e0 = idx4 * 4;
        int h = e0 / Ww, w = e0 % Ww;
        float4 v = ((const float4*)(x + xbase))[idx4];
        float4 cv = *(const float4*)&ch[h][0];
        float r0 = v.x * __expf(hatdot((w + 0) * (3.f / 191.f), cv));
        float r1 = v.y * __expf(hatdot((w + 1) * (3.f / 191.f), cv));
        float r2 = v.z * __expf(hatdot((w + 2) * (3.f / 191.f), cv));
        float r3 = v.w * __expf(hatdot((w + 3) * (3.f / 191.f), cv));
        u32 p0 = (u32)f2bf(r0) | ((u32)f2bf(r1) << 16);
        u32 p1 = (u32)f2bf(r2) | ((u32)f2bf(r3) << 16);
        u32* dst = (u32*)&P1[h * P1S + w];    // h*194+w even -> 4B aligned
        dst[0] = p0; dst[1] = p1;
    }
    __syncthreads();

    // --- phase 2: W-blur IN PLACE. wave owns rows wv*24..wv*24+23.
    //     lane = (r4: 4 rows) x (cc: 16 chunks of 12 outputs).
    float kw[KK];
    #pragma unroll
    for (int t = 0; t < KK; t++) kw[t] = kern[(b * 3 + 2) * KK + t];
    {
        const int wv = tid >> 6, ln = tid & 63;
        const int r4 = ln >> 4, cc = ln & 15;
        const int w0 = cc * 12;
        #pragma unroll
        for (int it = 0; it < 6; it++) {
            int row = wv * 24 + it * 4 + r4;
            float win[36];
            #pragma unroll
            for (int i = 0; i < 36; i++) {
                int wi = min(max(w0 - RR + i, 0), Ww - 1);
                win[i] = bf2f(P1[row * P1S + wi]);
            }
            u32 pk[6];
            #pragma unroll
            for (int m = 0; m < 6; m++) {
                float a0 = 0.f, a1 = 0.f;
                #pragma unroll
                for (int t = 0; t < KK; t++) {
                    a0 += win[2 * m + t] * kw[t];
                    a1 += win[2 * m + 1 + t] * kw[t];
                }
                pk[m] = (u32)f2bf(a0) | ((u32)f2bf(a1) << 16);
            }
            u32* dst = (u32*)&P1[row * P1S + w0];   // reads done (regs) before writes
            #pragma unroll
            for (int m = 0; m < 6; m++) dst[m] = pk[m];
        }
    }
    __syncthreads();

    // --- phase 3: H-blur (column windows), write bf16 plane to global ---
    float kh[KK];
    #pragma unroll
    for (int t = 0; t < KK; t++) kh[t] = kern[(b * 3 + 1) * KK + t];
    const size_t obase = ((size_t)b * Dd + d) * (size_t)(Hh * Ww);
    #pragma unroll
    for (int it = 0; it < 6; it++) {
        int item = it * 512 + tid;            // 0..3071
        int c2 = item / Ww;                   // 0..15 (uniform per wave)
        int col = item % Ww;
        int hb = c2 * 12;
        float win[36];
        #pragma unroll
        for (int i = 0; i < 36; i++) {
            int hi = min(max(hb - RR + i, 0), Hh - 1);
            win[i] = bf2f(P1[hi * P1S + col]);
        }
        #pragma unroll
        for (int j = 0; j < 12; j++) {
            float a = 0.f;
            #pragma unroll
            for (int t = 0; t < KK; t++) a += win[j + t] * kh[t];
            outB[obase + (size_t)(hb + j) * Ww + col] = f2bf(a);
        }
    }
}

// ---------------------------------------------------------------------------
// Kernel 2: blur along D. bf16 -> f32 final. Tile 32d x 2h x 192w.
// Loads 768B contiguous per d-row; stores 1536B contiguous per d-out.
// ---------------------------------------------------------------------------
__global__ __launch_bounds__(256) void pass_d_kernel(
    const u16* __restrict__ in, float* __restrict__ out,
    const float* __restrict__ kern) {
    __shared__ u16 sIn[56 * 2 * 192];        // 43008 B
    const int tid = threadIdx.x;
    const int d0 = blockIdx.x * 32;
    const int h0 = blockIdx.y * 2;
    const int b  = blockIdx.z;
    float kd[KK];
    #pragma unroll
    for (int t = 0; t < KK; t++) kd[t] = kern[b * 3 * KK + t];
    // load 56 rows x (2h x 192w) = 2688 uint4
    for (int k = 0; k < 11; k++) {
        int idx = tid + k * 256;
        if (idx < 2688) {
            int r = idx / 48, seg = idx % 48;
            int dd = min(max(d0 + r - RR, 0), Dd - 1);
            const uint4* src = (const uint4*)(in + (((size_t)b * Dd + dd) * Hh + h0) * (size_t)Ww);
            ((uint4*)sIn)[r * 48 + seg] = src[seg];
        }
    }
    __syncthreads();
    const int tx = tid & 63, ty = tid >> 6;
    const int ob = ty * 8;                   // 8 d-outputs per thread
    #pragma unroll
    for (int c = 0; c < 3; c++) {
        #pragma unroll
        for (int hh = 0; hh < 2; hh++) {
            const int col = c * 64 + tx;
            float win[32];
            #pragma unroll
            for (int i = 0; i < 32; i++)
                win[i] = bf2f(sIn[(ob + i) * 384 + hh * 192 + col]);
            float acc[8];
            #pragma unroll
            for (int j = 0; j < 8; j++) acc[j] = 0.0f;
            #pragma unroll
            for (int t = 0; t < KK; t++) {
                float kv = kd[t];
                #pragma unroll
                for (int j = 0; j < 8; j++) acc[j] += kv * win[j + t];
            }
            #pragma unroll
            for (int j = 0; j < 8; j++)
                out[(((size_t)b * Dd + (d0 + ob + j)) * Hh + (h0 + hh)) * (size_t)Ww + col] = acc[j];
        }
    }
}

// ---------------------------------------------------------------------------
// Kernel 3: label remap -> written as float values (harness reads f32)
// ---------------------------------------------------------------------------
__global__ __launch_bounds__(256) void remap_kernel(
    const int4* __restrict__ labels, float4* __restrict__ out,
    const int* __restrict__ mapping, int n4) {
    int i = blockIdx.x * blockDim.x + threadIdx.x;
    int stride = gridDim.x * blockDim.x;
    for (; i < n4; i += stride) {
        int4 l = labels[i];
        float4 o;
        o.x = (float)mapping[min(max(l.x, 0), 127)];
        o.y = (float)mapping[min(max(l.y, 0), 127)];
        o.z = (float)mapping[min(max(l.z, 0), 127)];
        o.w = (float)mapping[min(max(l.w, 0), 127)];
        out[i] = o;
    }
}

extern "C" void kernel_launch(void* const* d_in, const int* in_sizes, int n_in,
                              void* d_out, int out_size, void* d_ws, size_t ws_size,
                              hipStream_t stream) {
    const float* x          = (const float*)d_in[0];
    const float* small_bias = (const float*)d_in[1];
    const float* sigma01    = (const float*)d_in[2];
    const int*   labels     = (const int*)d_in[3];
    const int*   src        = (const int*)d_in[4];
    const int*   dst        = (const int*)d_in[5];

    float* out     = (float*)d_out;
    float* img     = out;                   // first VOL f32
    float* lab_out = out + (size_t)VOL;     // second VOL f32
    u16*   Bbuf    = (u16*)lab_out;         // bf16 intermediate, overwritten by remap

    float* kern    = (float*)d_ws;                    // 300 floats
    int*   mapping = (int*)((float*)d_ws + 384);      // 128 ints

    setup_tables_kernel<<<1, 128, 0, stream>>>(sigma01, src, dst, kern, mapping);

    // fused bias*exp + W + H: x(f32) -> Bbuf(bf16)
    pass_wh_kernel<<<dim3(Dd, Bc), 512, 0, stream>>>(x, Bbuf, kern, small_bias);
    // D-blur: Bbuf -> img (f32 final)
    pass_d_kernel<<<dim3(Dd / 32, Hh / 2, Bc), 256, 0, stream>>>(Bbuf, img, kern);
    // labels remap (after pass_d consumed Bbuf)
    remap_kernel<<<2048, 256, 0, stream>>>((const int4*)labels, (float4*)lab_out,
                                           mapping, VOL / 4);
}

// Round 4
// 172.391 us; speedup vs baseline: 1.3088x; 1.0451x over previous
//
#include <hip/hip_runtime.h>
#include <hip/hip_fp16.h>
#include <cstdint>
#include <cstddef>

#define Bc 4
#define Dd 192
#define Hh 192
#define Ww 192
#define KK 25
#define RR 12          // K//2
#define VOL (Bc*Dd*Hh*Ww)   // 28,311,552

typedef unsigned short u16;
typedef unsigned int   u32;

// ---------------------------------------------------------------------------
// Kernel 0: per-(batch,axis) Gaussian kernels [12][25] (f32 + packed half2)
// + label mapping [128]
// ---------------------------------------------------------------------------
__global__ void setup_tables_kernel(const float* __restrict__ sigma01,
                                    const int* __restrict__ src,
                                    const int* __restrict__ dst,
                                    float* __restrict__ kern,
                                    u32* __restrict__ kern2,
                                    int* __restrict__ mapping) {
    int t = threadIdx.x;
    if (t < 128) mapping[t] = 0;
    __syncthreads();
    if (t < 32) {
        int s = src[t];
        if (s >= 0 && s < 128) mapping[s] = dst[t];
    }
    if (t < Bc * 3) {
        float sig = sigma01[t] * 3.0f;          // MAX_SIGMA
        float s = fmaxf(sig, 1e-3f);
        float g[KK];
        float sum = 0.0f;
        #pragma unroll
        for (int i = 0; i < KK; i++) {
            float a = (float)(i - RR);
            float v = expf(-0.5f * a * a / (s * s));
            g[i] = v; sum += v;
        }
        float inv = 1.0f / sum;
        #pragma unroll
        for (int i = 0; i < KK; i++) {
            float v = g[i] * inv;
            if (sig < 0.01f) v = (i == RR) ? 1.0f : 0.0f;   // delta
            kern[t * KK + i] = v;
            u16 hb = __builtin_bit_cast(u16, __float2half(v));
            kern2[t * KK + i] = (u32)hb | ((u32)hb << 16);
        }
    }
}

// ---------------------------------------------------------------------------
// Kernel 1: bias*exp + W-blur. f32 in -> f16 out. Block 256, tile 8 h-rows.
// Wave covers 2 rows x 32 chunks of 6 outputs (win[30], 5 reads/output).
// ---------------------------------------------------------------------------
__global__ __launch_bounds__(256) void pass_w_kernel(
    const float* __restrict__ x, u16* __restrict__ outA,
    const float* __restrict__ kern, const float* __restrict__ sb) {
    __shared__ float s[8][217];                         // 6944 B (2-way banks)
    __shared__ __attribute__((aligned(16))) float ch[8][4];
    __shared__ __attribute__((aligned(16))) u16 sOut[8 * Ww];   // 3072 B
    const int tid = threadIdx.x;
    const int h0 = blockIdx.x * 8;
    const int d  = blockIdx.y;
    const int b  = blockIdx.z;

    // per-row bias coefficients (d,h collapsed; *0.7 folded): 32 threads
    if (tid < 32) {
        int r = tid >> 2, k = tid & 3;
        float pos_d = d * (3.0f / 191.0f);
        int   id0   = min((int)pos_d, 2);
        float fd    = pos_d - (float)id0;
        float pos_h = (h0 + r) * (3.0f / 191.0f);
        float w0h = fmaxf(0.f, 1.f - fabsf(pos_h));
        float w1h = fmaxf(0.f, 1.f - fabsf(pos_h - 1.f));
        float w2h = fmaxf(0.f, 1.f - fabsf(pos_h - 2.f));
        float w3h = fmaxf(0.f, 1.f - fabsf(pos_h - 3.f));
        const float* sbA = sb + b * 64 + id0 * 16;
        float sj0 = (1.f - fd) * sbA[k]      + fd * sbA[16 + k];
        float sj1 = (1.f - fd) * sbA[4 + k]  + fd * sbA[20 + k];
        float sj2 = (1.f - fd) * sbA[8 + k]  + fd * sbA[24 + k];
        float sj3 = (1.f - fd) * sbA[12 + k] + fd * sbA[28 + k];
        ch[r][k] = (w0h * sj0 + w1h * sj1 + w2h * sj2 + w3h * sj3) * 0.7f;
    }
    __syncthreads();

    const size_t base = (((size_t)b * Dd + d) * Hh + h0) * (size_t)Ww;
    // load 8 rows x 192 f32 = 384 float4, bias*exp, scatter to LDS rows
    #pragma unroll
    for (int k = 0; k < 2; k++) {
        int i4 = k * 256 + tid;
        if (i4 < 384) {
            int e0 = i4 * 4;
            int r = e0 / Ww, w = e0 % Ww;
            float4 v = ((const float4*)(x + base))[i4];
            float4 cv = *(const float4*)&ch[r][0];
            #pragma unroll
            for (int j = 0; j < 4; j++) {
                float pw = (w + j) * (3.0f / 191.0f);
                float b0 = fmaxf(0.f, 1.f - fabsf(pw));
                float b1 = fmaxf(0.f, 1.f - fabsf(pw - 1.f));
                float b2 = fmaxf(0.f, 1.f - fabsf(pw - 2.f));
                float b3 = fmaxf(0.f, 1.f - fabsf(pw - 3.f));
                float bias = b0 * cv.x + b1 * cv.y + b2 * cv.z + b3 * cv.w;
                float val = (j == 0 ? v.x : j == 1 ? v.y : j == 2 ? v.z : v.w);
                s[r][RR + w + j] = val * __expf(bias);
            }
        }
    }
    __syncthreads();
    if (tid < 96) {                       // replicate halos: 8 rows x 12 each side
        int r = tid / 12, i = tid % 12;
        s[r][i] = s[r][RR];
    } else if (tid < 192) {
        int u = tid - 96;
        int r = u / 12, i = u % 12;
        s[r][RR + Ww + i] = s[r][RR + Ww - 1];
    }
    __syncthreads();

    float kw[KK];
    #pragma unroll
    for (int t = 0; t < KK; t++) kw[t] = kern[(b * 3 + 2) * KK + t];  // W axis

    const int wv = tid >> 6, ln = tid & 63;
    const int rr = ln >> 5, c = ln & 31;
    const int row = wv * 2 + rr;
    const int w0 = c * 6;
    float win[30];
    #pragma unroll
    for (int i = 0; i < 30; i++) win[i] = s[row][w0 + i];
    float acc[6];
    #pragma unroll
    for (int j = 0; j < 6; j++) acc[j] = 0.0f;
    #pragma unroll
    for (int t = 0; t < KK; t++) {
        float kv = kw[t];
        #pragma unroll
        for (int j = 0; j < 6; j++) acc[j] += kv * win[j + t];
    }
    #pragma unroll
    for (int j = 0; j < 6; j++)
        sOut[row * Ww + w0 + j] = __builtin_bit_cast(u16, __float2half(acc[j]));
    __syncthreads();
    // 8 rows x 192 f16 = 3072 B contiguous
    if (tid < 192)
        ((uint4*)(outA + base))[tid] = ((const uint4*)sOut)[tid];
}

// ---------------------------------------------------------------------------
// Kernel 2: H-blur, f16 -> f16 with packed half2 FMA (2 adjacent cols/lane).
// Block 192, tile 32h x 96w. LDS = raw f16 tile (no converts).
// ---------------------------------------------------------------------------
__global__ __launch_bounds__(192) void pass_h_kernel(
    const u16* __restrict__ in, u16* __restrict__ out,
    const u32* __restrict__ kern2) {
    __shared__ __attribute__((aligned(16))) u16 T[56 * 96];   // 10752 B
    const int tid = threadIdx.x;
    const int w0 = blockIdx.x * 96;
    const int h0 = blockIdx.y * 32;
    const int bd = blockIdx.z;
    const int d = bd % Dd, b = bd / Dd;
    const size_t plane = ((size_t)b * Dd + d) * (size_t)(Hh * Ww);
    // load 56 rows x 12 uint4 (192B contiguous per row)
    #pragma unroll
    for (int k = 0; k < 4; k++) {
        int idx = k * 192 + tid;
        if (idx < 672) {
            int r = idx / 12, sg = idx % 12;
            int hh = min(max(h0 + r - RR, 0), Hh - 1);
            ((uint4*)T)[idx] = *(const uint4*)(in + plane + (size_t)hh * Ww + w0 + sg * 8);
        }
    }
    __syncthreads();
    __half2 k2[KK];
    #pragma unroll
    for (int t = 0; t < KK; t++)
        k2[t] = __builtin_bit_cast(__half2, kern2[(b * 3 + 1) * KK + t]);  // H axis
    const int p = tid % 48;          // column pair
    const int g = tid / 48;          // h-group
    const int ob = g * 8;
    const __half2* Th = (const __half2*)T;
    __half2 win2[32];
    #pragma unroll
    for (int i = 0; i < 32; i++) win2[i] = Th[(ob + i) * 48 + p];
    __half2 acc2[8];
    #pragma unroll
    for (int j = 0; j < 8; j++) acc2[j] = __float2half2_rn(0.0f);
    #pragma unroll
    for (int t = 0; t < KK; t++) {
        __half2 kv = k2[t];
        #pragma unroll
        for (int j = 0; j < 8; j++) acc2[j] = __hfma2(kv, win2[j + t], acc2[j]);
    }
    #pragma unroll
    for (int j = 0; j < 8; j++)
        *(u32*)(out + plane + (size_t)(h0 + ob + j) * Ww + w0 + 2 * p) =
            __builtin_bit_cast(u32, acc2[j]);
}

// ---------------------------------------------------------------------------
// Kernel 3: D-blur, f16 -> f32 final, packed half2 FMA.
// Block 192, tile 32d x 96w at fixed (b,h).
// ---------------------------------------------------------------------------
__global__ __launch_bounds__(192) void pass_d_kernel(
    const u16* __restrict__ in, float* __restrict__ out,
    const u32* __restrict__ kern2) {
    __shared__ __attribute__((aligned(16))) u16 T[56 * 96];
    const int tid = threadIdx.x;
    const int w0 = blockIdx.x * 96;
    const int d0 = blockIdx.y * 32;
    const int bh = blockIdx.z;
    const int h = bh % Hh, b = bh / Hh;
    #pragma unroll
    for (int k = 0; k < 4; k++) {
        int idx = k * 192 + tid;
        if (idx < 672) {
            int r = idx / 12, sg = idx % 12;
            int dd = min(max(d0 + r - RR, 0), Dd - 1);
            ((uint4*)T)[idx] = *(const uint4*)(in + (((size_t)b * Dd + dd) * Hh + h) * (size_t)Ww + w0 + sg * 8);
        }
    }
    __syncthreads();
    __half2 k2[KK];
    #pragma unroll
    for (int t = 0; t < KK; t++)
        k2[t] = __builtin_bit_cast(__half2, kern2[(b * 3 + 0) * KK + t]);  // D axis
    const int p = tid % 48;
    const int g = tid / 48;
    const int ob = g * 8;
    const __half2* Th = (const __half2*)T;
    __half2 win2[32];
    #pragma unroll
    for (int i = 0; i < 32; i++) win2[i] = Th[(ob + i) * 48 + p];
    __half2 acc2[8];
    #pragma unroll
    for (int j = 0; j < 8; j++) acc2[j] = __float2half2_rn(0.0f);
    #pragma unroll
    for (int t = 0; t < KK; t++) {
        __half2 kv = k2[t];
        #pragma unroll
        for (int j = 0; j < 8; j++) acc2[j] = __hfma2(kv, win2[j + t], acc2[j]);
    }
    #pragma unroll
    for (int j = 0; j < 8; j++) {
        float2 f2 = __half22float2(acc2[j]);
        *(float2*)(out + (((size_t)b * Dd + (d0 + ob + j)) * Hh + h) * (size_t)Ww + w0 + 2 * p) = f2;
    }
}

// ---------------------------------------------------------------------------
// Kernel 4: label remap -> written as float values (harness reads f32)
// ---------------------------------------------------------------------------
__global__ __launch_bounds__(256) void remap_kernel(
    const int4* __restrict__ labels, float4* __restrict__ out,
    const int* __restrict__ mapping, int n4) {
    int i = blockIdx.x * blockDim.x + threadIdx.x;
    int stride = gridDim.x * blockDim.x;
    for (; i < n4; i += stride) {
        int4 l = labels[i];
        float4 o;
        o.x = (float)mapping[min(max(l.x, 0), 127)];
        o.y = (float)mapping[min(max(l.y, 0), 127)];
        o.z = (float)mapping[min(max(l.z, 0), 127)];
        o.w = (float)mapping[min(max(l.w, 0), 127)];
        out[i] = o;
    }
}

extern "C" void kernel_launch(void* const* d_in, const int* in_sizes, int n_in,
                              void* d_out, int out_size, void* d_ws, size_t ws_size,
                              hipStream_t stream) {
    const float* x          = (const float*)d_in[0];
    const float* small_bias = (const float*)d_in[1];
    const float* sigma01    = (const float*)d_in[2];
    const int*   labels     = (const int*)d_in[3];
    const int*   src        = (const int*)d_in[4];
    const int*   dst        = (const int*)d_in[5];

    float* out     = (float*)d_out;
    float* img     = out;                   // first VOL f32
    float* lab_out = out + (size_t)VOL;     // second VOL f32
    // two f16 ping-pong volumes fill the labels half (2*VOL*2B = VOL*4B)
    u16* A  = (u16*)lab_out;
    u16* Bb = A + (size_t)VOL;

    float* kern    = (float*)d_ws;                    // 300 f32
    u32*   kern2   = (u32*)((float*)d_ws + 384);      // 300 u32 (packed half2)
    int*   mapping = (int*)((float*)d_ws + 768);      // 128 ints

    setup_tables_kernel<<<1, 128, 0, stream>>>(sigma01, src, dst, kern, kern2, mapping);

    // W-pass (bias*exp fused): x(f32) -> A(f16)
    pass_w_kernel<<<dim3(Hh / 8, Dd, Bc), 256, 0, stream>>>(x, A, kern, small_bias);
    // H-pass: A -> B (f16, half2-packed FMA)
    pass_h_kernel<<<dim3(Ww / 96, Hh / 32, Bc * Dd), 192, 0, stream>>>(A, Bb, kern2);
    // D-pass: B -> img (f32 final, half2-packed FMA)
    pass_d_kernel<<<dim3(Ww / 96, Dd / 32, Bc * Hh), 192, 0, stream>>>(Bb, img, kern2);
    // labels remap (after pass_d consumed B; overwrites A/B region)
    remap_kernel<<<2048, 256, 0, stream>>>((const int4*)labels, (float4*)lab_out,
                                           mapping, VOL / 4);
}

// Round 5
// 170.718 us; speedup vs baseline: 1.3216x; 1.0098x over previous
//
#include <hip/hip_runtime.h>
#include <hip/hip_fp16.h>
#include <cstdint>
#include <cstddef>

#define Bc 4
#define Dd 192
#define Hh 192
#define Ww 192
#define KK 25
#define RR 12          // K//2
#define VOL (Bc*Dd*Hh*Ww)   // 28,311,552
#define SH 98          // u16 LDS row stride for h/d tiles: 49 banks (odd) -> de-aliased

typedef unsigned short u16;
typedef unsigned int   u32;

// ---------------------------------------------------------------------------
// Kernel 0: per-(batch,axis) Gaussian kernels [12][25] (f32 + packed half2)
// + label mapping [128]  (mapping logic kept bit-identical to passing rounds)
// ---------------------------------------------------------------------------
__global__ void setup_tables_kernel(const float* __restrict__ sigma01,
                                    const int* __restrict__ src,
                                    const int* __restrict__ dst,
                                    float* __restrict__ kern,
                                    u32* __restrict__ kern2,
                                    int* __restrict__ mapping) {
    int t = threadIdx.x;
    if (t < 128) mapping[t] = 0;
    __syncthreads();
    if (t < 32) {
        int s = src[t];
        if (s >= 0 && s < 128) mapping[s] = dst[t];
    }
    if (t < Bc * 3) {
        float sig = sigma01[t] * 3.0f;          // MAX_SIGMA
        float s = fmaxf(sig, 1e-3f);
        float g[KK];
        float sum = 0.0f;
        #pragma unroll
        for (int i = 0; i < KK; i++) {
            float a = (float)(i - RR);
            float v = expf(-0.5f * a * a / (s * s));
            g[i] = v; sum += v;
        }
        float inv = 1.0f / sum;
        #pragma unroll
        for (int i = 0; i < KK; i++) {
            float v = g[i] * inv;
            if (sig < 0.01f) v = (i == RR) ? 1.0f : 0.0f;   // delta
            kern[t * KK + i] = v;
            u16 hb = __builtin_bit_cast(u16, __float2half(v));
            kern2[t * KK + i] = (u32)hb | ((u32)hb << 16);
        }
    }
}

// ---------------------------------------------------------------------------
// Kernel 1: bias*exp + W-blur. f32 in -> f16 out. Block 192, tile 8 h-rows.
// Conv windows read as ds_read_b128 (8 outputs / 8 b128 reads / thread);
// each thread stores its 8 f16 outputs as one uint4 directly to global.
// ---------------------------------------------------------------------------
__global__ __launch_bounds__(192) void pass_w_kernel(
    const float* __restrict__ x, u16* __restrict__ outA,
    const float* __restrict__ kern, const float* __restrict__ sb) {
    __shared__ __attribute__((aligned(16))) float s[8][244];   // 7808 B
    __shared__ __attribute__((aligned(16))) float ch[8][4];
    const int tid = threadIdx.x;
    const int h0 = blockIdx.x * 8;
    const int d  = blockIdx.y;
    const int b  = blockIdx.z;

    // W-axis taps (uniform, L2-hot)
    float kw[KK];
    const float* kp = kern + (b * 3 + 2) * KK;
    #pragma unroll
    for (int t = 0; t < KK; t++) kw[t] = kp[t];

    // per-row bias coefficients (d,h collapsed; *0.7 folded): 32 threads
    if (tid < 32) {
        int r = tid >> 2, k = tid & 3;
        float pos_d = d * (3.0f / 191.0f);
        int   id0   = min((int)pos_d, 2);
        float fd    = pos_d - (float)id0;
        float pos_h = (h0 + r) * (3.0f / 191.0f);
        float w0h = fmaxf(0.f, 1.f - fabsf(pos_h));
        float w1h = fmaxf(0.f, 1.f - fabsf(pos_h - 1.f));
        float w2h = fmaxf(0.f, 1.f - fabsf(pos_h - 2.f));
        float w3h = fmaxf(0.f, 1.f - fabsf(pos_h - 3.f));
        const float* sbA = sb + b * 64 + id0 * 16;
        float sj0 = (1.f - fd) * sbA[k]      + fd * sbA[16 + k];
        float sj1 = (1.f - fd) * sbA[4 + k]  + fd * sbA[20 + k];
        float sj2 = (1.f - fd) * sbA[8 + k]  + fd * sbA[24 + k];
        float sj3 = (1.f - fd) * sbA[12 + k] + fd * sbA[28 + k];
        ch[r][k] = (w0h * sj0 + w1h * sj1 + w2h * sj2 + w3h * sj3) * 0.7f;
    }
    __syncthreads();

    const size_t base = (((size_t)b * Dd + d) * Hh + h0) * (size_t)Ww;
    // load 8 rows x 48 float4, bias*exp, b128-write to LDS (idx 12+4*w4: 16B ok)
    #pragma unroll
    for (int k = 0; k < 2; k++) {
        int i4 = k * 192 + tid;               // 0..383
        int r = i4 / 48, w4 = i4 % 48;
        int w = 4 * w4;
        float4 v = ((const float4*)(x + base))[i4];
        float4 cv = *(const float4*)&ch[r][0];
        float rs[4];
        #pragma unroll
        for (int j = 0; j < 4; j++) {
            float pw = (w + j) * (3.0f / 191.0f);
            float b0 = fmaxf(0.f, 1.f - fabsf(pw));
            float b1 = fmaxf(0.f, 1.f - fabsf(pw - 1.f));
            float b2 = fmaxf(0.f, 1.f - fabsf(pw - 2.f));
            float b3 = fmaxf(0.f, 1.f - fabsf(pw - 3.f));
            float bias = b0 * cv.x + b1 * cv.y + b2 * cv.z + b3 * cv.w;
            float val = (j == 0 ? v.x : j == 1 ? v.y : j == 2 ? v.z : v.w);
            rs[j] = val * __expf(bias);
        }
        *(float4*)&s[r][RR + w] = make_float4(rs[0], rs[1], rs[2], rs[3]);
    }
    __syncthreads();
    // replicate halos: 8 rows x 12 each side, 192 threads exactly
    if (tid < 96) {
        int r = tid / 12, i = tid % 12;
        s[r][i] = s[r][RR];
    } else {
        int u = tid - 96;
        int r = u / 12, i = u % 12;
        s[r][RR + Ww + i] = s[r][RR + Ww - 1];
    }
    __syncthreads();

    // conv: thread -> (row, 8-output chunk); window = 32 floats = 8 b128 reads
    const int row = tid / 24, c = tid % 24;
    float win[32];
    #pragma unroll
    for (int i = 0; i < 8; i++) {
        float4 q = *(const float4*)&s[row][8 * c + 4 * i];
        win[4 * i + 0] = q.x; win[4 * i + 1] = q.y;
        win[4 * i + 2] = q.z; win[4 * i + 3] = q.w;
    }
    float acc[8];
    #pragma unroll
    for (int j = 0; j < 8; j++) acc[j] = 0.0f;
    #pragma unroll
    for (int t = 0; t < KK; t++) {
        float kv = kw[t];
        #pragma unroll
        for (int j = 0; j < 8; j++) acc[j] += kv * win[j + t];
    }
    u32 o[4];
    #pragma unroll
    for (int m = 0; m < 4; m++) {
        u16 lo = __builtin_bit_cast(u16, __float2half(acc[2 * m]));
        u16 hi = __builtin_bit_cast(u16, __float2half(acc[2 * m + 1]));
        o[m] = (u32)lo | ((u32)hi << 16);
    }
    uint4 vv; vv.x = o[0]; vv.y = o[1]; vv.z = o[2]; vv.w = o[3];
    *(uint4*)(outA + base + row * Ww + 8 * c) = vv;
}

// ---------------------------------------------------------------------------
// Kernel 2: H-blur, f16 -> f16, half2 FMA. Block 192, tile 64h x 96w.
// LDS stride SH=98 u16 (odd bank count) -> conflict-free column b32 reads.
// ---------------------------------------------------------------------------
__global__ __launch_bounds__(192) void pass_h_kernel(
    const u16* __restrict__ in, u16* __restrict__ out,
    const u32* __restrict__ kern2) {
    __shared__ __attribute__((aligned(16))) u16 T[88 * SH];   // 17248 B
    const int tid = threadIdx.x;
    const int w0 = blockIdx.x * 96;
    const int h0 = blockIdx.y * 64;
    const int bd = blockIdx.z;               // b*Dd + d
    const int b = bd / Dd;
    u32 k2[KK];
    const u32* kp = kern2 + (b * 3 + 1) * KK;
    #pragma unroll
    for (int t = 0; t < KK; t++) k2[t] = kp[t];
    const size_t plane = (size_t)bd * (size_t)(Hh * Ww);
    // load 88 rows x 12 uint4 (192B contiguous per row); b32 LDS writes (stride 98)
    #pragma unroll
    for (int k = 0; k < 6; k++) {
        int idx = k * 192 + tid;
        if (idx < 1056) {
            int r = idx / 12, sg = idx % 12;
            int hh = min(max(h0 + r - RR, 0), Hh - 1);
            uint4 v = *(const uint4*)(in + plane + (size_t)hh * Ww + w0 + sg * 8);
            u32* p = (u32*)&T[r * SH + sg * 8];
            p[0] = v.x; p[1] = v.y; p[2] = v.z; p[3] = v.w;
        }
    }
    __syncthreads();
    const int p = tid % 48;                  // half2 column (2 w)
    const int g0 = tid / 48;                 // 0..3
    #pragma unroll
    for (int cc = 0; cc < 2; cc++) {
        const int g = g0 + cc * 4;           // 0..7
        const int ob = g * 8;
        u32 win[32];
        #pragma unroll
        for (int i = 0; i < 32; i++) win[i] = *(const u32*)&T[(ob + i) * SH + 2 * p];
        __half2 acc[8];
        #pragma unroll
        for (int j = 0; j < 8; j++) acc[j] = __float2half2_rn(0.0f);
        #pragma unroll
        for (int t = 0; t < KK; t++) {
            __half2 kv = __builtin_bit_cast(__half2, k2[t]);
            #pragma unroll
            for (int j = 0; j < 8; j++)
                acc[j] = __hfma2(kv, __builtin_bit_cast(__half2, win[j + t]), acc[j]);
        }
        #pragma unroll
        for (int j = 0; j < 8; j++)
            *(u32*)(out + plane + (size_t)(h0 + ob + j) * Ww + w0 + 2 * p) =
                __builtin_bit_cast(u32, acc[j]);
    }
}

// ---------------------------------------------------------------------------
// Kernel 3: D-blur (f16 -> f32 final) FUSED with label remap.
// z < Bc*Hh: d-blur block (tile 64d x 96w at fixed b,h).
// z >= Bc*Hh: remap block (grid-stride over labels).
// ---------------------------------------------------------------------------
#define RMAP_Z 192
__global__ __launch_bounds__(192) void pass_d_remap_kernel(
    const u16* __restrict__ in, float* __restrict__ img,
    const u32* __restrict__ kern2,
    const int4* __restrict__ labels, float4* __restrict__ lab_out,
    const int* __restrict__ mapping) {
    const int z = blockIdx.z;
    if (z >= Bc * Hh) {
        // ---- remap part: 1152 blocks x 192 thr, 32 iters ----
        int rb = (z - Bc * Hh) * 6 + blockIdx.y * 2 + blockIdx.x;
        const int NT = RMAP_Z * 6 * 192;
        const int n4 = VOL / 4;
        for (int i = rb * 192 + threadIdx.x; i < n4; i += NT) {
            int4 l = labels[i];
            float4 o;
            o.x = (float)mapping[min(max(l.x, 0), 127)];
            o.y = (float)mapping[min(max(l.y, 0), 127)];
            o.z = (float)mapping[min(max(l.z, 0), 127)];
            o.w = (float)mapping[min(max(l.w, 0), 127)];
            lab_out[i] = o;
        }
        return;
    }
    // ---- d-blur part ----
    __shared__ __attribute__((aligned(16))) u16 T[88 * SH];
    const int tid = threadIdx.x;
    const int w0 = blockIdx.x * 96;
    const int d0 = blockIdx.y * 64;
    const int h = z % Hh, b = z / Hh;
    u32 k2[KK];
    const u32* kp = kern2 + b * 3 * KK;
    #pragma unroll
    for (int t = 0; t < KK; t++) k2[t] = kp[t];
    #pragma unroll
    for (int k = 0; k < 6; k++) {
        int idx = k * 192 + tid;
        if (idx < 1056) {
            int r = idx / 12, sg = idx % 12;
            int dd = min(max(d0 + r - RR, 0), Dd - 1);
            uint4 v = *(const uint4*)(in + (((size_t)b * Dd + dd) * Hh + h) * (size_t)Ww + w0 + sg * 8);
            u32* p = (u32*)&T[r * SH + sg * 8];
            p[0] = v.x; p[1] = v.y; p[2] = v.z; p[3] = v.w;
        }
    }
    __syncthreads();
    const int p = tid % 48;
    const int g0 = tid / 48;
    #pragma unroll
    for (int cc = 0; cc < 2; cc++) {
        const int g = g0 + cc * 4;
        const int ob = g * 8;
        u32 win[32];
        #pragma unroll
        for (int i = 0; i < 32; i++) win[i] = *(const u32*)&T[(ob + i) * SH + 2 * p];
        __half2 acc[8];
        #pragma unroll
        for (int j = 0; j < 8; j++) acc[j] = __float2half2_rn(0.0f);
        #pragma unroll
        for (int t = 0; t < KK; t++) {
            __half2 kv = __builtin_bit_cast(__half2, k2[t]);
            #pragma unroll
            for (int j = 0; j < 8; j++)
                acc[j] = __hfma2(kv, __builtin_bit_cast(__half2, win[j + t]), acc[j]);
        }
        #pragma unroll
        for (int j = 0; j < 8; j++) {
            float2 f = __half22float2(acc[j]);
            *(float2*)(img + (((size_t)b * Dd + (d0 + ob + j)) * Hh + h) * (size_t)Ww + w0 + 2 * p) = f;
        }
    }
}

extern "C" void kernel_launch(void* const* d_in, const int* in_sizes, int n_in,
                              void* d_out, int out_size, void* d_ws, size_t ws_size,
                              hipStream_t stream) {
    const float* x          = (const float*)d_in[0];
    const float* small_bias = (const float*)d_in[1];
    const float* sigma01    = (const float*)d_in[2];
    const int*   labels     = (const int*)d_in[3];
    const int*   src        = (const int*)d_in[4];
    const int*   dst        = (const int*)d_in[5];

    float* out     = (float*)d_out;
    float* img     = out;                   // first VOL f32
    float* lab_out = out + (size_t)VOL;     // second VOL f32

    float* kern    = (float*)d_ws;                    // 300 f32
    u32*   kern2   = (u32*)((float*)d_ws + 384);      // 300 u32 (packed half2)
    int*   mapping = (int*)((float*)d_ws + 768);      // 128 ints
    u16*   A       = (u16*)((char*)d_ws + 8192);      // f16 volume, VOL elems
    u16*   Bb      = A + (size_t)VOL;                 // f16 volume, VOL elems

    setup_tables_kernel<<<1, 128, 0, stream>>>(sigma01, src, dst, kern, kern2, mapping);

    // W-pass (bias*exp fused): x(f32) -> A(f16)
    pass_w_kernel<<<dim3(Hh / 8, Dd, Bc), 192, 0, stream>>>(x, A, kern, small_bias);
    // H-pass: A -> Bb (f16, half2 FMA, 64-row tiles)
    pass_h_kernel<<<dim3(Ww / 96, Hh / 64, Bc * Dd), 192, 0, stream>>>(A, Bb, kern2);
    // D-pass + label remap fused: Bb -> img (f32), labels -> lab_out
    pass_d_remap_kernel<<<dim3(Ww / 96, Dd / 64, Bc * Hh + RMAP_Z), 192, 0, stream>>>(
        Bb, img, kern2, (const int4*)labels, (float4*)lab_out, mapping);
}

// Round 6
// 156.107 us; speedup vs baseline: 1.4453x; 1.0936x over previous
//
#include <hip/hip_runtime.h>
#include <hip/hip_fp16.h>
#include <cstdint>
#include <cstddef>

#define Bc 4
#define Dd 192
#define Hh 192
#define Ww 192
#define KK 25
#define RR 12          // K//2
#define VOL (Bc*Dd*Hh*Ww)   // 28,311,552
#define SP 216         // u16 row stride of WH plane (192 data + 12+12 halo)
#define SPU (SP/2)     // 108 u32
#define SH 98          // u16 LDS row stride for d tiles

typedef unsigned short u16;
typedef unsigned int   u32;

// ---------------------------------------------------------------------------
// Kernel 0: per-(batch,axis) Gaussian kernels [12][25] (f32 + packed half2)
// + label mapping [128]
// ---------------------------------------------------------------------------
__global__ void setup_tables_kernel(const float* __restrict__ sigma01,
                                    const int* __restrict__ src,
                                    const int* __restrict__ dst,
                                    float* __restrict__ kern,
                                    u32* __restrict__ kern2,
                                    int* __restrict__ mapping) {
    int t = threadIdx.x;
    if (t < 128) mapping[t] = 0;
    __syncthreads();
    if (t < 32) {
        int s = src[t];
        if (s >= 0 && s < 128) mapping[s] = dst[t];
    }
    if (t < Bc * 3) {
        float sig = sigma01[t] * 3.0f;          // MAX_SIGMA
        float s = fmaxf(sig, 1e-3f);
        float g[KK];
        float sum = 0.0f;
        #pragma unroll
        for (int i = 0; i < KK; i++) {
            float a = (float)(i - RR);
            float v = expf(-0.5f * a * a / (s * s));
            g[i] = v; sum += v;
        }
        float inv = 1.0f / sum;
        #pragma unroll
        for (int i = 0; i < KK; i++) {
            float v = g[i] * inv;
            if (sig < 0.01f) v = (i == RR) ? 1.0f : 0.0f;   // delta
            kern[t * KK + i] = v;
            u16 hb = __builtin_bit_cast(u16, __float2half(v));
            kern2[t * KK + i] = (u32)hb | ((u32)hb << 16);
        }
    }
}

// ---------------------------------------------------------------------------
// Kernel 1: FUSED bias*exp + W-blur (in-place, wave-owned rows) + H-blur
// + label-remap tail. One (b,d) plane per 1024-thread block; plane in LDS f16.
// x(f32) -> Bb(f16); labels -> lab_out(f32).
// ---------------------------------------------------------------------------
__global__ __launch_bounds__(1024) void pass_wh_remap_kernel(
    const float* __restrict__ x, u16* __restrict__ outB,
    const float* __restrict__ kern, const u32* __restrict__ kern2,
    const float* __restrict__ sb,
    const int4* __restrict__ labels, float4* __restrict__ lab_out,
    const int* __restrict__ mapping) {
    __shared__ u16 P[Hh * SP];                               // 82944 B
    __shared__ __attribute__((aligned(16))) float ch[Hh][4]; // 3072 B
    const int tid = threadIdx.x;
    const int d = blockIdx.x;
    const int b = blockIdx.y;

    // --- phase 0: per-h bias coefficients (d,h collapsed; *0.7 folded) ---
    if (tid < Hh * 4) {
        int r = tid >> 2, k = tid & 3;
        float pos_d = d * (3.0f / 191.0f);
        int   id0   = min((int)pos_d, 2);
        float fd    = pos_d - (float)id0;
        float pos_h = r * (3.0f / 191.0f);
        float w0h = fmaxf(0.f, 1.f - fabsf(pos_h));
        float w1h = fmaxf(0.f, 1.f - fabsf(pos_h - 1.f));
        float w2h = fmaxf(0.f, 1.f - fabsf(pos_h - 2.f));
        float w3h = fmaxf(0.f, 1.f - fabsf(pos_h - 3.f));
        const float* sbA = sb + b * 64 + id0 * 16;
        float sj0 = (1.f - fd) * sbA[k]      + fd * sbA[16 + k];
        float sj1 = (1.f - fd) * sbA[4 + k]  + fd * sbA[20 + k];
        float sj2 = (1.f - fd) * sbA[8 + k]  + fd * sbA[24 + k];
        float sj3 = (1.f - fd) * sbA[12 + k] + fd * sbA[28 + k];
        ch[r][k] = (w0h * sj0 + w1h * sj1 + w2h * sj2 + w3h * sj3) * 0.7f;
    }
    __syncthreads();

    // --- phase 1: load plane (f32), bias*exp, pack f16 into P (+W halos) ---
    const size_t xbase = ((size_t)b * Dd + d) * (size_t)(Hh * Ww);
    #pragma unroll
    for (int it = 0; it < 9; it++) {
        int i4 = it * 1024 + tid;             // 0..9215
        int r = i4 / 48, w4 = i4 % 48;
        int w = 4 * w4;
        float4 v = ((const float4*)(x + xbase))[i4];
        float4 cv = *(const float4*)&ch[r][0];
        float rs[4];
        #pragma unroll
        for (int j = 0; j < 4; j++) {
            float pw = (w + j) * (3.0f / 191.0f);
            float b0 = fmaxf(0.f, 1.f - fabsf(pw));
            float b1 = fmaxf(0.f, 1.f - fabsf(pw - 1.f));
            float b2 = fmaxf(0.f, 1.f - fabsf(pw - 2.f));
            float b3 = fmaxf(0.f, 1.f - fabsf(pw - 3.f));
            float bias = b0 * cv.x + b1 * cv.y + b2 * cv.z + b3 * cv.w;
            float val = (j == 0 ? v.x : j == 1 ? v.y : j == 2 ? v.z : v.w);
            rs[j] = val * __expf(bias);
        }
        u32 p0 = (u32)__builtin_bit_cast(u16, __float2half(rs[0])) |
                 ((u32)__builtin_bit_cast(u16, __float2half(rs[1])) << 16);
        u32 p1 = (u32)__builtin_bit_cast(u16, __float2half(rs[2])) |
                 ((u32)__builtin_bit_cast(u16, __float2half(rs[3])) << 16);
        u32* dstp = (u32*)&P[r * SP + RR + w];
        dstp[0] = p0; dstp[1] = p1;
        if (w4 == 0) {                        // left replicate halo (w=0)
            u16 hv = __builtin_bit_cast(u16, __float2half(rs[0]));
            u32 hh = (u32)hv | ((u32)hv << 16);
            u32* hp = (u32*)&P[r * SP];
            #pragma unroll
            for (int m = 0; m < 6; m++) hp[m] = hh;
        } else if (w4 == 47) {                // right replicate halo (w=191)
            u16 hv = __builtin_bit_cast(u16, __float2half(rs[3]));
            u32 hh = (u32)hv | ((u32)hv << 16);
            u32* hp = (u32*)&P[r * SP + RR + Ww];
            #pragma unroll
            for (int m = 0; m < 6; m++) hp[m] = hh;
        }
    }
    __syncthreads();

    // --- phase 2: W-blur IN PLACE. Wave wv owns rows 12wv..12wv+11.
    //     Lane = (r4: 2 rows) x (c: 32 chunks of 6 outputs); 6 iterations.
    //     All window reads (regs) precede writes in wave program order.
    {
        float kw[KK];
        const float* kp = kern + (b * 3 + 2) * KK;
        #pragma unroll
        for (int t = 0; t < KK; t++) kw[t] = kp[t];
        const int wv = tid >> 6, ln = tid & 63;
        const int r4 = ln >> 5, c = ln & 31;
        #pragma unroll
        for (int it = 0; it < 6; it++) {
            const int row = wv * 12 + it * 2 + r4;
            const u32* rp = (const u32*)&P[row * SP] + 3 * c;   // u16 pos 6c
            u32 wraw[15];
            #pragma unroll
            for (int i = 0; i < 15; i++) wraw[i] = rp[i];
            float win[30];
            #pragma unroll
            for (int i = 0; i < 15; i++) {
                float2 f = __half22float2(__builtin_bit_cast(__half2, wraw[i]));
                win[2 * i] = f.x; win[2 * i + 1] = f.y;
            }
            float acc[6];
            #pragma unroll
            for (int j = 0; j < 6; j++) acc[j] = 0.0f;
            #pragma unroll
            for (int t = 0; t < KK; t++) {
                float kv = kw[t];
                #pragma unroll
                for (int j = 0; j < 6; j++) acc[j] += kv * win[j + t];
            }
            u32* wp = (u32*)&P[row * SP + RR + 6 * c];
            #pragma unroll
            for (int m = 0; m < 3; m++) {
                wp[m] = (u32)__builtin_bit_cast(u16, __float2half(acc[2 * m])) |
                        ((u32)__builtin_bit_cast(u16, __float2half(acc[2 * m + 1])) << 16);
            }
        }
    }
    __syncthreads();

    // --- phase 3: H-blur (clamped column windows), write f16 plane out ---
    {
        u32 k2[KK];
        const u32* kp = kern2 + (b * 3 + 1) * KK;
        #pragma unroll
        for (int t = 0; t < KK; t++) k2[t] = kp[t];
        u32* outp = (u32*)(outB + xbase);
        #pragma unroll
        for (int it = 0; it < 2; it++) {
            int item = it * 1024 + tid;       // 0..1535
            if (item < 1536) {
                int p = item % 96;            // u32 column (2 w)
                int g = item / 96;            // 0..15
                int hb = g * 12;
                u32 win[36];
                #pragma unroll
                for (int i = 0; i < 36; i++) {
                    int rr = min(max(hb - RR + i, 0), Hh - 1);
                    win[i] = *((const u32*)&P[rr * SP] + 6 + p);
                }
                __half2 acc[12];
                #pragma unroll
                for (int j = 0; j < 12; j++) acc[j] = __float2half2_rn(0.0f);
                #pragma unroll
                for (int t = 0; t < KK; t++) {
                    __half2 kv = __builtin_bit_cast(__half2, k2[t]);
                    #pragma unroll
                    for (int j = 0; j < 12; j++)
                        acc[j] = __hfma2(kv, __builtin_bit_cast(__half2, win[j + t]), acc[j]);
                }
                #pragma unroll
                for (int j = 0; j < 12; j++)
                    outp[(hb + j) * 96 + p] = __builtin_bit_cast(u32, acc[j]);
            }
        }
    }

    // --- phase 4: label remap slice (overlaps other blocks' compute) ---
    {
        const int bid = b * Dd + d;           // 0..767
        int base = bid * 9216 + tid;
        #pragma unroll
        for (int it = 0; it < 9; it++) {
            int i = base + it * 1024;
            int4 l = labels[i];
            float4 o;
            o.x = (float)mapping[min(max(l.x, 0), 127)];
            o.y = (float)mapping[min(max(l.y, 0), 127)];
            o.z = (float)mapping[min(max(l.z, 0), 127)];
            o.w = (float)mapping[min(max(l.w, 0), 127)];
            lab_out[i] = o;
        }
    }
}

// ---------------------------------------------------------------------------
// Kernel 2: D-blur, f16 -> f32 final. Block 192, tile 64d x 96w at (b,h).
// ---------------------------------------------------------------------------
__global__ __launch_bounds__(192) void pass_d_kernel(
    const u16* __restrict__ in, float* __restrict__ img,
    const u32* __restrict__ kern2) {
    __shared__ __attribute__((aligned(16))) u16 T[88 * SH];
    const int tid = threadIdx.x;
    const int w0 = blockIdx.x * 96;
    const int d0 = blockIdx.y * 64;
    const int z = blockIdx.z;
    const int h = z % Hh, b = z / Hh;
    u32 k2[KK];
    const u32* kp = kern2 + b * 3 * KK;
    #pragma unroll
    for (int t = 0; t < KK; t++) k2[t] = kp[t];
    #pragma unroll
    for (int k = 0; k < 6; k++) {
        int idx = k * 192 + tid;
        if (idx < 1056) {
            int r = idx / 12, sg = idx % 12;
            int dd = min(max(d0 + r - RR, 0), Dd - 1);
            uint4 v = *(const uint4*)(in + (((size_t)b * Dd + dd) * Hh + h) * (size_t)Ww + w0 + sg * 8);
            u32* p = (u32*)&T[r * SH + sg * 8];
            p[0] = v.x; p[1] = v.y; p[2] = v.z; p[3] = v.w;
        }
    }
    __syncthreads();
    const int p = tid % 48;
    const int g0 = tid / 48;
    #pragma unroll
    for (int cc = 0; cc < 2; cc++) {
        const int g = g0 + cc * 4;
        const int ob = g * 8;
        u32 win[32];
        #pragma unroll
        for (int i = 0; i < 32; i++) win[i] = *(const u32*)&T[(ob + i) * SH + 2 * p];
        __half2 acc[8];
        #pragma unroll
        for (int j = 0; j < 8; j++) acc[j] = __float2half2_rn(0.0f);
        #pragma unroll
        for (int t = 0; t < KK; t++) {
            __half2 kv = __builtin_bit_cast(__half2, k2[t]);
            #pragma unroll
            for (int j = 0; j < 8; j++)
                acc[j] = __hfma2(kv, __builtin_bit_cast(__half2, win[j + t]), acc[j]);
        }
        #pragma unroll
        for (int j = 0; j < 8; j++) {
            float2 f = __half22float2(acc[j]);
            *(float2*)(img + (((size_t)b * Dd + (d0 + ob + j)) * Hh + h) * (size_t)Ww + w0 + 2 * p) = f;
        }
    }
}

extern "C" void kernel_launch(void* const* d_in, const int* in_sizes, int n_in,
                              void* d_out, int out_size, void* d_ws, size_t ws_size,
                              hipStream_t stream) {
    const float* x          = (const float*)d_in[0];
    const float* small_bias = (const float*)d_in[1];
    const float* sigma01    = (const float*)d_in[2];
    const int*   labels     = (const int*)d_in[3];
    const int*   src        = (const int*)d_in[4];
    const int*   dst        = (const int*)d_in[5];

    float* out     = (float*)d_out;
    float* img     = out;                   // first VOL f32
    float* lab_out = out + (size_t)VOL;     // second VOL f32

    float* kern    = (float*)d_ws;                    // 300 f32
    u32*   kern2   = (u32*)((float*)d_ws + 384);      // 300 u32 (packed half2)
    int*   mapping = (int*)((float*)d_ws + 768);      // 128 ints
    u16*   Bb      = (u16*)((char*)d_ws + 8192);      // f16 volume, VOL elems

    setup_tables_kernel<<<1, 128, 0, stream>>>(sigma01, src, dst, kern, kern2, mapping);

    // fused bias*exp + W + H (+ remap tail): x -> Bb, labels -> lab_out
    pass_wh_remap_kernel<<<dim3(Dd, Bc), 1024, 0, stream>>>(
        x, Bb, kern, kern2, small_bias,
        (const int4*)labels, (float4*)lab_out, mapping);
    // D-blur: Bb -> img (f32 final)
    pass_d_kernel<<<dim3(Ww / 96, Dd / 64, Bc * Hh), 192, 0, stream>>>(Bb, img, kern2);
}

// Round 7
// 152.073 us; speedup vs baseline: 1.4836x; 1.0265x over previous
//
#include <hip/hip_runtime.h>
#include <hip/hip_fp16.h>
#include <cstdint>
#include <cstddef>

#define Bc 4
#define Dd 192
#define Hh 192
#define Ww 192
#define KK 25
#define RR 12          // K//2
#define VOL (Bc*Dd*Hh*Ww)   // 28,311,552
#define SP 216         // u16 row stride of plane rows (192 data + 12+12 halo)
#define SPU (SP/2)     // 108 u32
#define SH 98          // u16 LDS row stride for d tiles
#define RIN 120        // input rows per half-plane block (96 out + 2*12 halo)

typedef unsigned short u16;
typedef unsigned int   u32;

// ---------------------------------------------------------------------------
// Kernel 0: per-(batch,axis) Gaussian kernels [12][25] (f32 + packed half2)
// + label mapping [128]
// ---------------------------------------------------------------------------
__global__ void setup_tables_kernel(const float* __restrict__ sigma01,
                                    const int* __restrict__ src,
                                    const int* __restrict__ dst,
                                    float* __restrict__ kern,
                                    u32* __restrict__ kern2,
                                    int* __restrict__ mapping) {
    int t = threadIdx.x;
    if (t < 128) mapping[t] = 0;
    __syncthreads();
    if (t < 32) {
        int s = src[t];
        if (s >= 0 && s < 128) mapping[s] = dst[t];
    }
    if (t < Bc * 3) {
        float sig = sigma01[t] * 3.0f;          // MAX_SIGMA
        float s = fmaxf(sig, 1e-3f);
        float g[KK];
        float sum = 0.0f;
        #pragma unroll
        for (int i = 0; i < KK; i++) {
            float a = (float)(i - RR);
            float v = expf(-0.5f * a * a / (s * s));
            g[i] = v; sum += v;
        }
        float inv = 1.0f / sum;
        #pragma unroll
        for (int i = 0; i < KK; i++) {
            float v = g[i] * inv;
            if (sig < 0.01f) v = (i == RR) ? 1.0f : 0.0f;   // delta
            kern[t * KK + i] = v;
            u16 hb = __builtin_bit_cast(u16, __float2half(v));
            kern2[t * KK + i] = (u32)hb | ((u32)hb << 16);
        }
    }
}

// ---------------------------------------------------------------------------
// Kernel 1: FUSED bias*exp + W-blur (in-place, wave-owned rows) + H-blur
// + label-remap tail. HALF-plane per 512-thread block: 96 output rows,
// 120 staged input rows (12-row halos, clamped at volume edges).
// LDS 52.8 KB -> 2-3 blocks/CU for cross-phase overlap.
// ---------------------------------------------------------------------------
__global__ __launch_bounds__(512) void pass_wh_remap_kernel(
    const float* __restrict__ x, u16* __restrict__ outB,
    const float* __restrict__ kern, const u32* __restrict__ kern2,
    const float* __restrict__ sb,
    const int4* __restrict__ labels, float4* __restrict__ lab_out,
    const int* __restrict__ mapping) {
    __shared__ u16 P[RIN * SP];                          // 51840 B
    __shared__ u32 ch[RIN][2];                           // 960 B (half2 x2)
    const int tid = threadIdx.x;
    const int hx = blockIdx.x;          // half: output rows [96hx, 96hx+96)
    const int d  = blockIdx.y;
    const int b  = blockIdx.z;

    // --- phase 0: per-input-row bias coefficients (d,h collapsed; *0.7) ---
    if (tid < RIN * 4) {
        int r = tid >> 2, k = tid & 3;
        int hrow = min(max(96 * hx - RR + r, 0), Hh - 1);
        float pos_d = d * (3.0f / 191.0f);
        int   id0   = min((int)pos_d, 2);
        float fd    = pos_d - (float)id0;
        float pos_h = hrow * (3.0f / 191.0f);
        float w0h = fmaxf(0.f, 1.f - fabsf(pos_h));
        float w1h = fmaxf(0.f, 1.f - fabsf(pos_h - 1.f));
        float w2h = fmaxf(0.f, 1.f - fabsf(pos_h - 2.f));
        float w3h = fmaxf(0.f, 1.f - fabsf(pos_h - 3.f));
        const float* sbA = sb + b * 64 + id0 * 16;
        float sj0 = (1.f - fd) * sbA[k]      + fd * sbA[16 + k];
        float sj1 = (1.f - fd) * sbA[4 + k]  + fd * sbA[20 + k];
        float sj2 = (1.f - fd) * sbA[8 + k]  + fd * sbA[24 + k];
        float sj3 = (1.f - fd) * sbA[12 + k] + fd * sbA[28 + k];
        float cv = (w0h * sj0 + w1h * sj1 + w2h * sj2 + w3h * sj3) * 0.7f;
        // pack: ch[r][0] = half2(c0,c1), ch[r][1] = half2(c2,c3)
        u16 hb = __builtin_bit_cast(u16, __float2half(cv));
        atomicAnd(&ch[r][k >> 1], ~(0xFFFFu << ((k & 1) * 16)));  // placeholder
        // NOTE: replaced below by direct write path
        (void)hb;
    }
    // simpler: one thread per row computes both packed words
    __syncthreads();
    if (tid < RIN) {
        int r = tid;
        int hrow = min(max(96 * hx - RR + r, 0), Hh - 1);
        float pos_d = d * (3.0f / 191.0f);
        int   id0   = min((int)pos_d, 2);
        float fd    = pos_d - (float)id0;
        float pos_h = hrow * (3.0f / 191.0f);
        float w0h = fmaxf(0.f, 1.f - fabsf(pos_h));
        float w1h = fmaxf(0.f, 1.f - fabsf(pos_h - 1.f));
        float w2h = fmaxf(0.f, 1.f - fabsf(pos_h - 2.f));
        float w3h = fmaxf(0.f, 1.f - fabsf(pos_h - 3.f));
        const float* sbA = sb + b * 64 + id0 * 16;
        float c[4];
        #pragma unroll
        for (int k = 0; k < 4; k++) {
            float sj0 = (1.f - fd) * sbA[k]      + fd * sbA[16 + k];
            float sj1 = (1.f - fd) * sbA[4 + k]  + fd * sbA[20 + k];
            float sj2 = (1.f - fd) * sbA[8 + k]  + fd * sbA[24 + k];
            float sj3 = (1.f - fd) * sbA[12 + k] + fd * sbA[28 + k];
            c[k] = (w0h * sj0 + w1h * sj1 + w2h * sj2 + w3h * sj3) * 0.7f;
        }
        ch[r][0] = (u32)__builtin_bit_cast(u16, __float2half(c[0])) |
                   ((u32)__builtin_bit_cast(u16, __float2half(c[1])) << 16);
        ch[r][1] = (u32)__builtin_bit_cast(u16, __float2half(c[2])) |
                   ((u32)__builtin_bit_cast(u16, __float2half(c[3])) << 16);
    }
    __syncthreads();

    // --- phase 1: load 120 rows (clamped), bias*exp, pack f16 into P ---
    const size_t pbase = ((size_t)b * Dd + d) * (size_t)(Hh * Ww);
    #pragma unroll
    for (int it = 0; it < 12; it++) {
        int i4 = it * 512 + tid;              // 0..6143, need < 5760
        if (i4 < RIN * 48) {
            int r = i4 / 48, w4 = i4 % 48;
            int w = 4 * w4;
            int hrow = min(max(96 * hx - RR + r, 0), Hh - 1);
            float4 v = *(const float4*)(x + pbase + (size_t)hrow * Ww + w);
            float2 cv01 = __half22float2(__builtin_bit_cast(__half2, ch[r][0]));
            float2 cv23 = __half22float2(__builtin_bit_cast(__half2, ch[r][1]));
            float rs[4];
            #pragma unroll
            for (int j = 0; j < 4; j++) {
                float pw = (w + j) * (3.0f / 191.0f);
                float b0 = fmaxf(0.f, 1.f - fabsf(pw));
                float b1 = fmaxf(0.f, 1.f - fabsf(pw - 1.f));
                float b2 = fmaxf(0.f, 1.f - fabsf(pw - 2.f));
                float b3 = fmaxf(0.f, 1.f - fabsf(pw - 3.f));
                float bias = b0 * cv01.x + b1 * cv01.y + b2 * cv23.x + b3 * cv23.y;
                float val = (j == 0 ? v.x : j == 1 ? v.y : j == 2 ? v.z : v.w);
                rs[j] = val * __expf(bias);
            }
            u32 p0 = (u32)__builtin_bit_cast(u16, __float2half(rs[0])) |
                     ((u32)__builtin_bit_cast(u16, __float2half(rs[1])) << 16);
            u32 p1 = (u32)__builtin_bit_cast(u16, __float2half(rs[2])) |
                     ((u32)__builtin_bit_cast(u16, __float2half(rs[3])) << 16);
            u32* dstp = (u32*)&P[r * SP + RR + w];
            dstp[0] = p0; dstp[1] = p1;
            if (w4 == 0) {                    // left replicate halo (w=0)
                u16 hv = __builtin_bit_cast(u16, __float2half(rs[0]));
                u32 hh = (u32)hv | ((u32)hv << 16);
                u32* hp = (u32*)&P[r * SP];
                #pragma unroll
                for (int m = 0; m < 6; m++) hp[m] = hh;
            } else if (w4 == 47) {            // right replicate halo (w=191)
                u16 hv = __builtin_bit_cast(u16, __float2half(rs[3]));
                u32 hh = (u32)hv | ((u32)hv << 16);
                u32* hp = (u32*)&P[r * SP + RR + Ww];
                #pragma unroll
                for (int m = 0; m < 6; m++) hp[m] = hh;
            }
        }
    }
    __syncthreads();

    // --- phase 2: W-blur IN PLACE. Wave wv owns rows [15wv, 15wv+15).
    //     Lane = (r4: 2 rows) x (c: 32 chunks of 6 outputs); reads precede
    //     writes in wave program order -> safe in-place.
    {
        float kw[KK];
        const float* kp = kern + (b * 3 + 2) * KK;
        #pragma unroll
        for (int t = 0; t < KK; t++) kw[t] = kp[t];
        const int wv = tid >> 6, ln = tid & 63;
        const int r4 = ln >> 5, c = ln & 31;
        #pragma unroll
        for (int it = 0; it < 8; it++) {
            const int lr = it * 2 + r4;
            if (lr < 15) {
                const int row = wv * 15 + lr;
                const u32* rp = (const u32*)&P[row * SP] + 3 * c;   // u16 pos 6c
                u32 wraw[15];
                #pragma unroll
                for (int i = 0; i < 15; i++) wraw[i] = rp[i];
                float win[30];
                #pragma unroll
                for (int i = 0; i < 15; i++) {
                    float2 f = __half22float2(__builtin_bit_cast(__half2, wraw[i]));
                    win[2 * i] = f.x; win[2 * i + 1] = f.y;
                }
                float acc[6];
                #pragma unroll
                for (int j = 0; j < 6; j++) acc[j] = 0.0f;
                #pragma unroll
                for (int t = 0; t < KK; t++) {
                    float kv = kw[t];
                    #pragma unroll
                    for (int j = 0; j < 6; j++) acc[j] += kv * win[j + t];
                }
                u32* wp = (u32*)&P[row * SP + RR + 6 * c];
                #pragma unroll
                for (int m = 0; m < 3; m++) {
                    wp[m] = (u32)__builtin_bit_cast(u16, __float2half(acc[2 * m])) |
                            ((u32)__builtin_bit_cast(u16, __float2half(acc[2 * m + 1])) << 16);
                }
            }
        }
    }
    __syncthreads();

    // --- phase 3: H-blur (halo rows pre-staged -> window is just lo+i),
    //     write f16 half-plane to global ---
    {
        u32 k2[KK];
        const u32* kp = kern2 + (b * 3 + 1) * KK;
        #pragma unroll
        for (int t = 0; t < KK; t++) k2[t] = kp[t];
        u32* outp = (u32*)(outB + pbase);
        #pragma unroll
        for (int it = 0; it < 2; it++) {
            int item = it * 512 + tid;        // 0..1023, need < 768
            if (item < 768) {
                int col = item % 96;          // u32 column (2 w)
                int g = item / 96;            // 0..7 (12-row output group)
                u32 win[36];
                #pragma unroll
                for (int i = 0; i < 36; i++)
                    win[i] = *((const u32*)&P[(g * 12 + i) * SP] + 6 + col);
                __half2 acc[12];
                #pragma unroll
                for (int j = 0; j < 12; j++) acc[j] = __float2half2_rn(0.0f);
                #pragma unroll
                for (int t = 0; t < KK; t++) {
                    __half2 kv = __builtin_bit_cast(__half2, k2[t]);
                    #pragma unroll
                    for (int j = 0; j < 12; j++)
                        acc[j] = __hfma2(kv, __builtin_bit_cast(__half2, win[j + t]), acc[j]);
                }
                #pragma unroll
                for (int j = 0; j < 12; j++)
                    outp[(96 * hx + g * 12 + j) * 96 + col] =
                        __builtin_bit_cast(u32, acc[j]);
            }
        }
    }

    // --- phase 4: label remap slice (overlaps other blocks' compute) ---
    {
        const int bid = ((b * Dd) + d) * 2 + hx;      // 0..1535
        int base = bid * 4608 + tid;
        #pragma unroll
        for (int it = 0; it < 9; it++) {
            int i = base + it * 512;
            int4 l = labels[i];
            float4 o;
            o.x = (float)mapping[min(max(l.x, 0), 127)];
            o.y = (float)mapping[min(max(l.y, 0), 127)];
            o.z = (float)mapping[min(max(l.z, 0), 127)];
            o.w = (float)mapping[min(max(l.w, 0), 127)];
            lab_out[i] = o;
        }
    }
}

// ---------------------------------------------------------------------------
// Kernel 2: D-blur, f16 -> f32 final. Block 192, tile 64d x 96w at (b,h).
// ---------------------------------------------------------------------------
__global__ __launch_bounds__(192) void pass_d_kernel(
    const u16* __restrict__ in, float* __restrict__ img,
    const u32* __restrict__ kern2) {
    __shared__ __attribute__((aligned(16))) u16 T[88 * SH];
    const int tid = threadIdx.x;
    const int w0 = blockIdx.x * 96;
    const int d0 = blockIdx.y * 64;
    const int z = blockIdx.z;
    const int h = z % Hh, b = z / Hh;
    u32 k2[KK];
    const u32* kp = kern2 + b * 3 * KK;
    #pragma unroll
    for (int t = 0; t < KK; t++) k2[t] = kp[t];
    #pragma unroll
    for (int k = 0; k < 6; k++) {
        int idx = k * 192 + tid;
        if (idx < 1056) {
            int r = idx / 12, sg = idx % 12;
            int dd = min(max(d0 + r - RR, 0), Dd - 1);
            uint4 v = *(const uint4*)(in + (((size_t)b * Dd + dd) * Hh + h) * (size_t)Ww + w0 + sg * 8);
            u32* p = (u32*)&T[r * SH + sg * 8];
            p[0] = v.x; p[1] = v.y; p[2] = v.z; p[3] = v.w;
        }
    }
    __syncthreads();
    const int p = tid % 48;
    const int g0 = tid / 48;
    #pragma unroll
    for (int cc = 0; cc < 2; cc++) {
        const int g = g0 + cc * 4;
        const int ob = g * 8;
        u32 win[32];
        #pragma unroll
        for (int i = 0; i < 32; i++) win[i] = *(const u32*)&T[(ob + i) * SH + 2 * p];
        __half2 acc[8];
        #pragma unroll
        for (int j = 0; j < 8; j++) acc[j] = __float2half2_rn(0.0f);
        #pragma unroll
        for (int t = 0; t < KK; t++) {
            __half2 kv = __builtin_bit_cast(__half2, k2[t]);
            #pragma unroll
            for (int j = 0; j < 8; j++)
                acc[j] = __hfma2(kv, __builtin_bit_cast(__half2, win[j + t]), acc[j]);
        }
        #pragma unroll
        for (int j = 0; j < 8; j++) {
            float2 f = __half22float2(acc[j]);
            *(float2*)(img + (((size_t)b * Dd + (d0 + ob + j)) * Hh + h) * (size_t)Ww + w0 + 2 * p) = f;
        }
    }
}

extern "C" void kernel_launch(void* const* d_in, const int* in_sizes, int n_in,
                              void* d_out, int out_size, void* d_ws, size_t ws_size,
                              hipStream_t stream) {
    const float* x          = (const float*)d_in[0];
    const float* small_bias = (const float*)d_in[1];
    const float* sigma01    = (const float*)d_in[2];
    const int*   labels     = (const int*)d_in[3];
    const int*   src        = (const int*)d_in[4];
    const int*   dst        = (const int*)d_in[5];

    float* out     = (float*)d_out;
    float* img     = out;                   // first VOL f32
    float* lab_out = out + (size_t)VOL;     // second VOL f32

    float* kern    = (float*)d_ws;                    // 300 f32
    u32*   kern2   = (u32*)((float*)d_ws + 384);      // 300 u32 (packed half2)
    int*   mapping = (int*)((float*)d_ws + 768);      // 128 ints
    u16*   Bb      = (u16*)((char*)d_ws + 8192);      // f16 volume, VOL elems

    setup_tables_kernel<<<1, 128, 0, stream>>>(sigma01, src, dst, kern, kern2, mapping);

    // fused bias*exp + W + H (+ remap tail): x -> Bb, labels -> lab_out
    pass_wh_remap_kernel<<<dim3(2, Dd, Bc), 512, 0, stream>>>(
        x, Bb, kern, kern2, small_bias,
        (const int4*)labels, (float4*)lab_out, mapping);
    // D-blur: Bb -> img (f32 final)
    pass_d_kernel<<<dim3(Ww / 96, Dd / 64, Bc * Hh), 192, 0, stream>>>(Bb, img, kern2);
}

// Round 8
// 141.235 us; speedup vs baseline: 1.5975x; 1.0767x over previous
//
#include <hip/hip_runtime.h>
#include <hip/hip_fp16.h>
#include <cstdint>
#include <cstddef>

#define Bc 4
#define Dd 192
#define Hh 192
#define Ww 192
#define KK 25
#define RR 12          // K//2
#define VOL (Bc*Dd*Hh*Ww)   // 28,311,552
#define SP 216         // u16 row stride of plane rows (12 halo + 192 + 12 halo)
#define SPU (SP/2)     // 108 u32
#define SH 98          // u16 LDS row stride for d tiles
#define RIN 120        // input rows per half-plane block (96 out + 2*12 halo)

typedef unsigned short u16;
typedef unsigned int   u32;

// ---------------------------------------------------------------------------
// Kernel 0: per-(batch,axis) Gaussian kernels [12][25] (f32 + packed half2)
// + label mapping [128]
// ---------------------------------------------------------------------------
__global__ void setup_tables_kernel(const float* __restrict__ sigma01,
                                    const int* __restrict__ src,
                                    const int* __restrict__ dst,
                                    float* __restrict__ kern,
                                    u32* __restrict__ kern2,
                                    int* __restrict__ mapping) {
    int t = threadIdx.x;
    if (t < 128) mapping[t] = 0;
    __syncthreads();
    if (t < 32) {
        int s = src[t];
        if (s >= 0 && s < 128) mapping[s] = dst[t];
    }
    if (t < Bc * 3) {
        float sig = sigma01[t] * 3.0f;          // MAX_SIGMA
        float s = fmaxf(sig, 1e-3f);
        float g[KK];
        float sum = 0.0f;
        #pragma unroll
        for (int i = 0; i < KK; i++) {
            float a = (float)(i - RR);
            float v = expf(-0.5f * a * a / (s * s));
            g[i] = v; sum += v;
        }
        float inv = 1.0f / sum;
        #pragma unroll
        for (int i = 0; i < KK; i++) {
            float v = g[i] * inv;
            if (sig < 0.01f) v = (i == RR) ? 1.0f : 0.0f;   // delta
            kern[t * KK + i] = v;
            u16 hb = __builtin_bit_cast(u16, __float2half(v));
            kern2[t * KK + i] = (u32)hb | ((u32)hb << 16);
        }
    }
}

// ---------------------------------------------------------------------------
// Kernel 1: FUSED bias*exp + W-blur (packed-pair, in-place) + H-blur
// + label-remap tail. Half-plane per 512-thread block.
// ---------------------------------------------------------------------------
__global__ __launch_bounds__(512) void pass_wh_remap_kernel(
    const float* __restrict__ x, u16* __restrict__ outB,
    const u32* __restrict__ kern2,
    const float* __restrict__ sb,
    const int4* __restrict__ labels, float4* __restrict__ lab_out,
    const int* __restrict__ mapping) {
    __shared__ u16 P[RIN * SP];                          // 51840 B
    __shared__ __attribute__((aligned(16))) float ch[RIN][4];  // 1920 B
    const int tid = threadIdx.x;
    const int hx = blockIdx.x;          // half: output rows [96hx, 96hx+96)
    const int d  = blockIdx.y;
    const int b  = blockIdx.z;

    // --- phase 0: per-input-row bias coefficients c[4] (d,h collapsed; *0.7) ---
    if (tid < RIN) {
        int r = tid;
        int hrow = min(max(96 * hx - RR + r, 0), Hh - 1);
        float pos_d = d * (3.0f / 191.0f);
        int   id0   = min((int)pos_d, 2);
        float fd    = pos_d - (float)id0;
        float pos_h = hrow * (3.0f / 191.0f);
        int   ih0   = min((int)pos_h, 2);
        float fh    = pos_h - (float)ih0;
        const float* sbA = sb + b * 64 + id0 * 16 + ih0 * 4;
        #pragma unroll
        for (int k = 0; k < 4; k++) {
            float v00 = sbA[k],      v01 = sbA[4 + k];
            float v10 = sbA[16 + k], v11 = sbA[20 + k];
            float vd0 = (1.f - fd) * v00 + fd * v10;
            float vd1 = (1.f - fd) * v01 + fd * v11;
            // k-th w-node coefficient after collapsing d AND h? No: collapse
            // d only per (id0), h via 2-node below would need c over h-nodes.
            // Here we collapse BOTH d and h: c[k] = interp over d,h of node k.
            ch[r][k] = ((1.f - fh) * vd0 + fh * vd1) * 0.7f;
        }
    }
    __syncthreads();

    // --- phase 1: load 120 rows (clamped), bias*exp (2-node w-interp), pack f16 ---
    const size_t pbase = ((size_t)b * Dd + d) * (size_t)(Hh * Ww);
    #pragma unroll
    for (int it = 0; it < 12; it++) {
        int i4 = it * 512 + tid;              // need < 5760
        if (i4 < RIN * 48) {
            int r = i4 / 48, w4 = i4 % 48;
            int w = 4 * w4;
            int hrow = min(max(96 * hx - RR + r, 0), Hh - 1);
            float4 v = *(const float4*)(x + pbase + (size_t)hrow * Ww + w);
            float4 cv = *(const float4*)&ch[r][0];
            float rs[4];
            #pragma unroll
            for (int j = 0; j < 4; j++) {
                float pw = (w + j) * (3.0f / 191.0f);
                bool s1 = pw >= 1.0f, s2 = pw >= 2.0f;
                float clo = s2 ? cv.z : (s1 ? cv.y : cv.x);
                float chi = s2 ? cv.w : (s1 ? cv.z : cv.y);
                float fb  = s2 ? 2.0f : (s1 ? 1.0f : 0.0f);
                float fw  = pw - fb;
                float bias = clo + fw * (chi - clo);
                float val = (j == 0 ? v.x : j == 1 ? v.y : j == 2 ? v.z : v.w);
                rs[j] = val * __expf(bias);
            }
            u32 p0 = (u32)__builtin_bit_cast(u16, __float2half(rs[0])) |
                     ((u32)__builtin_bit_cast(u16, __float2half(rs[1])) << 16);
            u32 p1 = (u32)__builtin_bit_cast(u16, __float2half(rs[2])) |
                     ((u32)__builtin_bit_cast(u16, __float2half(rs[3])) << 16);
            u32* dstp = (u32*)&P[r * SP + RR + w];
            dstp[0] = p0; dstp[1] = p1;
            if (w4 == 0) {                    // left replicate halo (w=0)
                u16 hv = __builtin_bit_cast(u16, __float2half(rs[0]));
                u32 hh = (u32)hv | ((u32)hv << 16);
                u32* hp = (u32*)&P[r * SP];
                #pragma unroll
                for (int m = 0; m < 6; m++) hp[m] = hh;
            } else if (w4 == 47) {            // right replicate halo (w=191)
                u16 hv = __builtin_bit_cast(u16, __float2half(rs[3]));
                u32 hh = (u32)hv | ((u32)hv << 16);
                u32* hp = (u32*)&P[r * SP + RR + Ww];
                #pragma unroll
                for (int m = 0; m < 6; m++) hp[m] = hh;
            }
        }
    }
    __syncthreads();

    // --- phase 2: W-blur IN PLACE, packed half2 pairs along w.
    //     Wave wv owns rows [15wv, 15wv+15). Lane = (r4: rows) x (c: 16
    //     chunks of 12 outputs = 6 output pairs). Window: 18 even pairs E,
    //     17 odd pairs O via alignbit. 25 hfma2 per output pair.
    {
        const u32* kw2 = kern2 + (b * 3 + 2) * KK;    // uniform -> SGPR loads
        const int wv = tid >> 6, ln = tid & 63;
        const int r4 = ln >> 4;        // 0..3
        const int c  = ln & 15;        // chunk: outputs [12c, 12c+12)
        #pragma unroll
        for (int it = 0; it < 4; it++) {
            const int lr = it * 4 + r4;
            if (lr < 15) {
                const int row = wv * 15 + lr;
                const u32* rp = (const u32*)P + row * SPU + 6 * c;  // u16 12c
                u32 E[18];
                #pragma unroll
                for (int j = 0; j < 18; j++) E[j] = rp[j];
                u32 O[17];
                #pragma unroll
                for (int j = 0; j < 17; j++)
                    O[j] = (E[j] >> 16) | (E[j + 1] << 16);   // v_alignbit
                __half2 acc[6];
                #pragma unroll
                for (int m = 0; m < 6; m++) acc[m] = __float2half2_rn(0.0f);
                #pragma unroll
                for (int s = 0; s < 13; s++) {
                    __half2 kv = __builtin_bit_cast(__half2, kw2[2 * s]);
                    #pragma unroll
                    for (int m = 0; m < 6; m++)
                        acc[m] = __hfma2(kv, __builtin_bit_cast(__half2, E[m + s]), acc[m]);
                }
                #pragma unroll
                for (int s = 0; s < 12; s++) {
                    __half2 kv = __builtin_bit_cast(__half2, kw2[2 * s + 1]);
                    #pragma unroll
                    for (int m = 0; m < 6; m++)
                        acc[m] = __hfma2(kv, __builtin_bit_cast(__half2, O[m + s]), acc[m]);
                }
                u32* wp = (u32*)P + row * SPU + 6 + 6 * c;
                #pragma unroll
                for (int m = 0; m < 6; m++)
                    wp[m] = __builtin_bit_cast(u32, acc[m]);
            }
        }
    }
    __syncthreads();

    // --- phase 3: H-blur (halo rows pre-staged), write f16 half-plane out ---
    {
        const u32* kh2 = kern2 + (b * 3 + 1) * KK;    // uniform -> SGPR
        u32* outp = (u32*)(outB + pbase);
        #pragma unroll
        for (int it = 0; it < 2; it++) {
            int item = it * 512 + tid;        // need < 768
            if (item < 768) {
                int col = item % 96;          // u32 column (2 w)
                int g = item / 96;            // 0..7 (12-row output group)
                u32 win[36];
                #pragma unroll
                for (int i = 0; i < 36; i++)
                    win[i] = *((const u32*)P + (g * 12 + i) * SPU + 6 + col);
                __half2 acc[12];
                #pragma unroll
                for (int j = 0; j < 12; j++) acc[j] = __float2half2_rn(0.0f);
                #pragma unroll
                for (int t = 0; t < KK; t++) {
                    __half2 kv = __builtin_bit_cast(__half2, kh2[t]);
                    #pragma unroll
                    for (int j = 0; j < 12; j++)
                        acc[j] = __hfma2(kv, __builtin_bit_cast(__half2, win[j + t]), acc[j]);
                }
                #pragma unroll
                for (int j = 0; j < 12; j++)
                    outp[(96 * hx + g * 12 + j) * 96 + col] =
                        __builtin_bit_cast(u32, acc[j]);
            }
        }
    }

    // --- phase 4: label remap slice (overlaps other blocks' compute) ---
    {
        const int bid = ((b * Dd) + d) * 2 + hx;      // 0..1535
        int base = bid * 4608 + tid;
        #pragma unroll
        for (int it = 0; it < 9; it++) {
            int i = base + it * 512;
            int4 l = labels[i];
            float4 o;
            o.x = (float)mapping[min(max(l.x, 0), 127)];
            o.y = (float)mapping[min(max(l.y, 0), 127)];
            o.z = (float)mapping[min(max(l.z, 0), 127)];
            o.w = (float)mapping[min(max(l.w, 0), 127)];
            lab_out[i] = o;
        }
    }
}

// ---------------------------------------------------------------------------
// Kernel 2: D-blur, f16 -> f32 final. Block 192, tile 64d x 96w at (b,h).
// ---------------------------------------------------------------------------
__global__ __launch_bounds__(192) void pass_d_kernel(
    const u16* __restrict__ in, float* __restrict__ img,
    const u32* __restrict__ kern2) {
    __shared__ __attribute__((aligned(16))) u16 T[88 * SH];
    const int tid = threadIdx.x;
    const int w0 = blockIdx.x * 96;
    const int d0 = blockIdx.y * 64;
    const int z = blockIdx.z;
    const int h = z % Hh, b = z / Hh;
    const u32* kp = kern2 + b * 3 * KK;               // uniform -> SGPR
    #pragma unroll
    for (int k = 0; k < 6; k++) {
        int idx = k * 192 + tid;
        if (idx < 1056) {
            int r = idx / 12, sg = idx % 12;
            int dd = min(max(d0 + r - RR, 0), Dd - 1);
            uint4 v = *(const uint4*)(in + (((size_t)b * Dd + dd) * Hh + h) * (size_t)Ww + w0 + sg * 8);
            u32* p = (u32*)&T[r * SH + sg * 8];
            p[0] = v.x; p[1] = v.y; p[2] = v.z; p[3] = v.w;
        }
    }
    __syncthreads();
    const int p = tid % 48;
    const int g0 = tid / 48;
    #pragma unroll
    for (int cc = 0; cc < 2; cc++) {
        const int g = g0 + cc * 4;
        const int ob = g * 8;
        u32 win[32];
        #pragma unroll
        for (int i = 0; i < 32; i++) win[i] = *(const u32*)&T[(ob + i) * SH + 2 * p];
        __half2 acc[8];
        #pragma unroll
        for (int j = 0; j < 8; j++) acc[j] = __float2half2_rn(0.0f);
        #pragma unroll
        for (int t = 0; t < KK; t++) {
            __half2 kv = __builtin_bit_cast(__half2, kp[t]);
            #pragma unroll
            for (int j = 0; j < 8; j++)
                acc[j] = __hfma2(kv, __builtin_bit_cast(__half2, win[j + t]), acc[j]);
        }
        #pragma unroll
        for (int j = 0; j < 8; j++) {
            float2 f = __half22float2(acc[j]);
            *(float2*)(img + (((size_t)b * Dd + (d0 + ob + j)) * Hh + h) * (size_t)Ww + w0 + 2 * p) = f;
        }
    }
}

extern "C" void kernel_launch(void* const* d_in, const int* in_sizes, int n_in,
                              void* d_out, int out_size, void* d_ws, size_t ws_size,
                              hipStream_t stream) {
    const float* x          = (const float*)d_in[0];
    const float* small_bias = (const float*)d_in[1];
    const float* sigma01    = (const float*)d_in[2];
    const int*   labels     = (const int*)d_in[3];
    const int*   src        = (const int*)d_in[4];
    const int*   dst        = (const int*)d_in[5];

    float* out     = (float*)d_out;
    float* img     = out;                   // first VOL f32
    float* lab_out = out + (size_t)VOL;     // second VOL f32

    float* kern    = (float*)d_ws;                    // 300 f32
    u32*   kern2   = (u32*)((float*)d_ws + 384);      // 300 u32 (packed half2)
    int*   mapping = (int*)((float*)d_ws + 768);      // 128 ints
    u16*   Bb      = (u16*)((char*)d_ws + 8192);      // f16 volume, VOL elems

    setup_tables_kernel<<<1, 128, 0, stream>>>(sigma01, src, dst, kern, kern2, mapping);

    // fused bias*exp + W + H (+ remap tail): x -> Bb, labels -> lab_out
    pass_wh_remap_kernel<<<dim3(2, Dd, Bc), 512, 0, stream>>>(
        x, Bb, kern2, small_bias,
        (const int4*)labels, (float4*)lab_out, mapping);
    // D-blur: Bb -> img (f32 final)
    pass_d_kernel<<<dim3(Ww / 96, Dd / 64, Bc * Hh), 192, 0, stream>>>(Bb, img, kern2);
}